// Round 1
// baseline (2238.718 us; speedup 1.0000x reference)
//
#include <hip/hip_runtime.h>
#include <hip/hip_bf16.h>

#define B_  2
#define S_  4096
#define E_  2048
#define H_  16
#define HD_ 128
#define QKDIM_ (H_*HD_)   // 2048

typedef __attribute__((ext_vector_type(8))) short bf16x8;
typedef __attribute__((ext_vector_type(4))) float f32x4;

static __device__ __forceinline__ short f2bf(float f) {
    unsigned int u = __builtin_bit_cast(unsigned int, f);
    unsigned int r = 0x7FFFu + ((u >> 16) & 1u);
    u += r;
    return (short)(u >> 16);
}

// ---------------- cast f32 -> bf16 (vectorized, grid-stride) ----------------
__global__ void cast_f32_bf16_kernel(const float* __restrict__ in,
                                     short* __restrict__ out, int n4) {
    int stride = gridDim.x * blockDim.x;
    for (int i = blockIdx.x * blockDim.x + threadIdx.x; i < n4; i += stride) {
        float4 v = ((const float4*)in)[i];
        short4 o;
        o.x = f2bf(v.x); o.y = f2bf(v.y); o.z = f2bf(v.z); o.w = f2bf(v.w);
        ((short4*)out)[i] = o;
    }
}

// ------------- transpose + cast: W[K,N] f32  ->  Wt[N,K] bf16 ---------------
__global__ void transpose_cast_kernel(const float* __restrict__ in,
                                      short* __restrict__ out, int K, int N) {
    __shared__ float tile[32][33];
    int nb = blockIdx.x * 32, kb = blockIdx.y * 32;
    int tx = threadIdx.x & 31, ty = threadIdx.x >> 5;   // 256 thr: 8 rows/pass
    for (int r = ty; r < 32; r += 8)
        tile[r][tx] = in[(size_t)(kb + r) * N + nb + tx];
    __syncthreads();
    for (int r = ty; r < 32; r += 8)
        out[(size_t)(nb + r) * K + kb + tx] = f2bf(tile[tx][r]);
}

// ------------- transpose V: [B*S, HD] bf16 -> [B][HD][S] bf16 ---------------
__global__ void transpose_v_kernel(const short* __restrict__ in,
                                   short* __restrict__ out) {
    __shared__ short tile[32][33];
    int b = blockIdx.z;
    int db = blockIdx.x * 32, sb = blockIdx.y * 32;
    int tx = threadIdx.x & 31, ty = threadIdx.x >> 5;
    for (int r = ty; r < 32; r += 8)
        tile[r][tx] = in[(size_t)(b * S_ + sb + r) * HD_ + db + tx];
    __syncthreads();
    for (int r = ty; r < 32; r += 8)
        out[((size_t)b * HD_ + db + r) * S_ + sb + tx] = tile[tx][r];
}

// ---------------- GEMM: C[M,N] = A[M,K] @ Bt[N,K]^T + bias[N] ---------------
// A,Bt bf16 row-major; 256 thr = 4 waves (2x2), 64x64 per wave, 128x128/block.
template <bool BF16OUT>
__global__ __launch_bounds__(256)
void gemm_kernel(const short* __restrict__ A, const short* __restrict__ Bt,
                 const float* __restrict__ bias, void* __restrict__ Cout,
                 int M, int N, int Kd) {
    int wave = threadIdx.x >> 6;
    int lane = threadIdx.x & 63;
    int wr = wave >> 1, wc = wave & 1;
    int row0 = blockIdx.y * 128 + wr * 64;
    int col0 = blockIdx.x * 128 + wc * 64;
    int lr = lane & 15;
    int lk = (lane >> 4) * 8;

    f32x4 acc[4][4] = {};
    for (int k0 = 0; k0 < Kd; k0 += 32) {
        bf16x8 af[4], bfr[4];
#pragma unroll
        for (int i = 0; i < 4; i++) {
            af[i]  = *(const bf16x8*)&A [(size_t)(row0 + i*16 + lr) * Kd + k0 + lk];
            bfr[i] = *(const bf16x8*)&Bt[(size_t)(col0 + i*16 + lr) * Kd + k0 + lk];
        }
#pragma unroll
        for (int i = 0; i < 4; i++)
#pragma unroll
            for (int j = 0; j < 4; j++)
                acc[i][j] = __builtin_amdgcn_mfma_f32_16x16x32_bf16(
                    af[i], bfr[j], acc[i][j], 0, 0, 0);
    }
    int crow = (lane >> 4) * 4;
    int ccol = lane & 15;
#pragma unroll
    for (int i = 0; i < 4; i++)
#pragma unroll
        for (int j = 0; j < 4; j++)
#pragma unroll
            for (int r = 0; r < 4; r++) {
                int row = row0 + i*16 + crow + r;
                int col = col0 + j*16 + ccol;
                float v = acc[i][j][r] + bias[col];
                if (BF16OUT)
                    ((short*)Cout)[(size_t)row * N + col] = f2bf(v);
                else
                    ((float*)Cout)[(size_t)row * N + col] = v;
            }
}

// --------------------------- flash MQA attention ----------------------------
// One wave per 16 q-rows; 32-key blocks; online softmax; P via LDS repack.
// Q: [B*S, 2048] bf16 (head h at col h*128); K: [B*S,128]; Vt: [B][128][S].
__global__ __launch_bounds__(256)
void attn_kernel(const short* __restrict__ Q, const short* __restrict__ Kb,
                 const short* __restrict__ Vt, short* __restrict__ Out) {
    __shared__ __align__(16) short plds_all[4][16][32];
    int wave = threadIdx.x >> 6;
    int lane = threadIdx.x & 63;
    int wid  = blockIdx.x * 4 + wave;
    int qt = wid & (S_/16 - 1);
    int bh = wid >> 8;
    int h  = bh & (H_ - 1);
    int b  = bh >> 4;
    int q0 = qt * 16;
    int lr = lane & 15;
    int lk = (lane >> 4) * 8;
    short (*plds)[32] = plds_all[wave];

    // Q fragments for the whole K-dim (4 k-steps of 32)
    bf16x8 qf[4];
    const short* qbase = Q + (size_t)(b * S_ + q0 + lr) * QKDIM_ + h * HD_;
#pragma unroll
    for (int kk = 0; kk < 4; kk++)
        qf[kk] = *(const bf16x8*)&qbase[kk * 32 + lk];

    float m[4], l[4];
#pragma unroll
    for (int r = 0; r < 4; r++) { m[r] = -1e30f; l[r] = 0.f; }
    f32x4 o[8] = {};

    int crow = (lane >> 4) * 4;
    int ccol = lane & 15;
    const float scale = 0.08838834764831845f;  // 1/sqrt(128)

    int kbmax = (q0 + 15) / 32;
    for (int kb = 0; kb <= kbmax; kb++) {
        int key0 = kb * 32;
        // S = Q K^T  (two 16-key halves)
        f32x4 s0 = {}, s1 = {};
        const short* kbase = Kb + (size_t)(b * S_ + key0) * HD_;
#pragma unroll
        for (int kk = 0; kk < 4; kk++) {
            bf16x8 kf0 = *(const bf16x8*)&kbase[(size_t)lr        * HD_ + kk*32 + lk];
            bf16x8 kf1 = *(const bf16x8*)&kbase[(size_t)(16 + lr) * HD_ + kk*32 + lk];
            s0 = __builtin_amdgcn_mfma_f32_16x16x32_bf16(qf[kk], kf0, s0, 0, 0, 0);
            s1 = __builtin_amdgcn_mfma_f32_16x16x32_bf16(qf[kk], kf1, s1, 0, 0, 0);
        }
        // scale + causal mask + row max
        float p0[4], p1[4], mb[4];
#pragma unroll
        for (int r = 0; r < 4; r++) {
            int qrow = q0 + crow + r;
            float v0 = s0[r] * scale; if (key0      + ccol > qrow) v0 = -1e30f;
            float v1 = s1[r] * scale; if (key0 + 16 + ccol > qrow) v1 = -1e30f;
            p0[r] = v0; p1[r] = v1;
            mb[r] = fmaxf(v0, v1);
        }
#pragma unroll
        for (int off = 1; off < 16; off <<= 1)
#pragma unroll
            for (int r = 0; r < 4; r++)
                mb[r] = fmaxf(mb[r], __shfl_xor(mb[r], off, 16));
        // online softmax update
        float corr[4], rs[4];
#pragma unroll
        for (int r = 0; r < 4; r++) {
            float mn = fmaxf(m[r], mb[r]);
            corr[r] = __expf(m[r] - mn);
            m[r] = mn;
            float e0 = __expf(p0[r] - mn);
            float e1 = __expf(p1[r] - mn);
            plds[crow + r][ccol]      = f2bf(e0);
            plds[crow + r][ccol + 16] = f2bf(e1);
            rs[r] = e0 + e1;
        }
#pragma unroll
        for (int off = 1; off < 16; off <<= 1)
#pragma unroll
            for (int r = 0; r < 4; r++)
                rs[r] += __shfl_xor(rs[r], off, 16);
#pragma unroll
        for (int r = 0; r < 4; r++)
            l[r] = l[r] * corr[r] + rs[r];
#pragma unroll
        for (int j = 0; j < 8; j++)
#pragma unroll
            for (int r = 0; r < 4; r++)
                o[j][r] *= corr[r];
        // P (A-layout) from LDS; PV
        bf16x8 pf = *(const bf16x8*)&plds[lr][lk];
        const short* vtb = Vt + (size_t)b * HD_ * S_ + key0;
#pragma unroll
        for (int j = 0; j < 8; j++) {
            bf16x8 vf = *(const bf16x8*)&vtb[(size_t)(j*16 + lr) * S_ + lk];
            o[j] = __builtin_amdgcn_mfma_f32_16x16x32_bf16(pf, vf, o[j], 0, 0, 0);
        }
    }
    // epilogue: normalize, store bf16
#pragma unroll
    for (int j = 0; j < 8; j++)
#pragma unroll
        for (int r = 0; r < 4; r++) {
            int row = q0 + crow + r;
            int d   = j * 16 + ccol;
            float v = o[j][r] / l[r];
            Out[(size_t)(b * S_ + row) * QKDIM_ + h * HD_ + d] = f2bf(v);
        }
}

// ------------------------------- launcher -----------------------------------
extern "C" void kernel_launch(void* const* d_in, const int* in_sizes, int n_in,
                              void* d_out, int out_size, void* d_ws, size_t ws_size,
                              hipStream_t stream) {
    (void)in_sizes; (void)n_in; (void)out_size; (void)ws_size;
    const float* x  = (const float*)d_in[0];
    const float* Wq = (const float*)d_in[1];
    const float* bq = (const float*)d_in[2];
    const float* Wk = (const float*)d_in[3];
    const float* bk = (const float*)d_in[4];
    const float* Wv = (const float*)d_in[5];
    const float* bv = (const float*)d_in[6];
    const float* Wo = (const float*)d_in[7];
    const float* bo = (const float*)d_in[8];
    float* out = (float*)d_out;

    char* ws = (char*)d_ws;
    const size_t M = (size_t)B_ * S_;          // 8192
    short* xb   = (short*)(ws);                               // 33,554,432 B
    short* Wq_t = (short*)(ws + 33554432);                    //  8,388,608
    short* Wk_t = (short*)(ws + 41943040);                    //    524,288
    short* Wv_t = (short*)(ws + 42467328);                    //    524,288
    short* Wo_t = (short*)(ws + 42991616);                    //  8,388,608
    short* Qb   = (short*)(ws + 51380224);                    // 33,554,432
    short* Kbuf = (short*)(ws + 84934656);                    //  2,097,152
    short* Vbuf = (short*)(ws + 87031808);                    //  2,097,152
    short* Vtb  = (short*)(ws + 89128960);                    //  2,097,152
    short* attn = (short*)(ws + 91226112);                    // 33,554,432
    // total: 124,780,544 B

    // casts / transposes
    cast_f32_bf16_kernel<<<2048, 256, 0, stream>>>(x, xb, (int)(M * E_ / 4));
    transpose_cast_kernel<<<dim3(E_/32,  E_/32), 256, 0, stream>>>(Wq, Wq_t, E_, QKDIM_);
    transpose_cast_kernel<<<dim3(HD_/32, E_/32), 256, 0, stream>>>(Wk, Wk_t, E_, HD_);
    transpose_cast_kernel<<<dim3(HD_/32, E_/32), 256, 0, stream>>>(Wv, Wv_t, E_, HD_);
    transpose_cast_kernel<<<dim3(E_/32,  E_/32), 256, 0, stream>>>(Wo, Wo_t, QKDIM_, E_);

    // projections
    gemm_kernel<true><<<dim3(QKDIM_/128, M/128), 256, 0, stream>>>(
        xb, Wq_t, bq, Qb, (int)M, QKDIM_, E_);
    gemm_kernel<true><<<dim3(1, M/128), 256, 0, stream>>>(
        xb, Wk_t, bk, Kbuf, (int)M, HD_, E_);
    gemm_kernel<true><<<dim3(1, M/128), 256, 0, stream>>>(
        xb, Wv_t, bv, Vbuf, (int)M, HD_, E_);

    transpose_v_kernel<<<dim3(HD_/32, S_/32, B_), 256, 0, stream>>>(Vbuf, Vtb);

    // attention: B*H*(S/16) = 8192 waves -> 2048 blocks of 4 waves
    attn_kernel<<<2048, 256, 0, stream>>>(Qb, Kbuf, Vtb, attn);

    // output projection (f32 out)
    gemm_kernel<false><<<dim3(E_/128, M/128), 256, 0, stream>>>(
        attn, Wo_t, bo, out, (int)M, E_, E_);
}

// Round 2
// 1475.246 us; speedup vs baseline: 1.5175x; 1.5175x over previous
//
#include <hip/hip_runtime.h>
#include <hip/hip_bf16.h>

#define B_  2
#define S_  4096
#define E_  2048
#define H_  16
#define HD_ 128
#define QKDIM_ (H_*HD_)   // 2048
#define QKVLD  2304       // fused QKV row stride (2048 Q + 128 K + 128 V)

typedef __attribute__((ext_vector_type(8))) short bf16x8;
typedef __attribute__((ext_vector_type(4))) float f32x4;

static __device__ __forceinline__ short f2bf(float f) {
    unsigned int u = __builtin_bit_cast(unsigned int, f);
    unsigned int r = 0x7FFFu + ((u >> 16) & 1u);
    u += r;
    return (short)(u >> 16);
}

// ---------------- cast f32 -> bf16 (vectorized, grid-stride) ----------------
__global__ void cast_f32_bf16_kernel(const float* __restrict__ in,
                                     short* __restrict__ out, int n4) {
    int stride = gridDim.x * blockDim.x;
    for (int i = blockIdx.x * blockDim.x + threadIdx.x; i < n4; i += stride) {
        float4 v = ((const float4*)in)[i];
        short4 o;
        o.x = f2bf(v.x); o.y = f2bf(v.y); o.z = f2bf(v.z); o.w = f2bf(v.w);
        ((short4*)out)[i] = o;
    }
}

// ------------- transpose + cast: W[K,N] f32  ->  Wt[N,K] bf16 ---------------
__global__ void transpose_cast_kernel(const float* __restrict__ in,
                                      short* __restrict__ out, int K, int N) {
    __shared__ float tile[32][33];
    int nb = blockIdx.x * 32, kb = blockIdx.y * 32;
    int tx = threadIdx.x & 31, ty = threadIdx.x >> 5;   // 256 thr: 8 rows/pass
    for (int r = ty; r < 32; r += 8)
        tile[r][tx] = in[(size_t)(kb + r) * N + nb + tx];
    __syncthreads();
    for (int r = ty; r < 32; r += 8)
        out[(size_t)(nb + r) * K + kb + tx] = f2bf(tile[tx][r]);
}

// ---------------------- concat bias [bq|bk|bv] -> f32[2304] -----------------
__global__ void concat_bias_kernel(const float* __restrict__ bq,
                                   const float* __restrict__ bk,
                                   const float* __restrict__ bv,
                                   float* __restrict__ out) {
    int i = blockIdx.x * 256 + threadIdx.x;
    if (i >= QKVLD) return;
    if (i < QKDIM_)            out[i] = bq[i];
    else if (i < QKDIM_ + HD_) out[i] = bk[i - QKDIM_];
    else                       out[i] = bv[i - QKDIM_ - HD_];
}

// --------- transpose V: QKV[B*S, ld] (V cols) bf16 -> [B][HD][S] bf16 -------
__global__ void transpose_v_kernel(const short* __restrict__ in,
                                   short* __restrict__ out, int ld) {
    __shared__ short tile[32][33];
    int b = blockIdx.z;
    int db = blockIdx.x * 32, sb = blockIdx.y * 32;
    int tx = threadIdx.x & 31, ty = threadIdx.x >> 5;
    for (int r = ty; r < 32; r += 8)
        tile[r][tx] = in[(size_t)(b * S_ + sb + r) * ld + db + tx];
    __syncthreads();
    for (int r = ty; r < 32; r += 8)
        out[((size_t)b * HD_ + db + r) * S_ + sb + tx] = tile[tx][r];
}

// ---------------- GEMM: C[M,N] = A[M,K] @ Bt[N,K]^T + bias[N] ---------------
template <bool BF16OUT>
__global__ __launch_bounds__(256)
void gemm_kernel(const short* __restrict__ A, const short* __restrict__ Bt,
                 const float* __restrict__ bias, void* __restrict__ Cout,
                 int M, int N, int Kd) {
    int wave = threadIdx.x >> 6;
    int lane = threadIdx.x & 63;
    int wr = wave >> 1, wc = wave & 1;
    int row0 = blockIdx.y * 128 + wr * 64;
    int col0 = blockIdx.x * 128 + wc * 64;
    int lr = lane & 15;
    int lk = (lane >> 4) * 8;

    f32x4 acc[4][4] = {};
    for (int k0 = 0; k0 < Kd; k0 += 32) {
        bf16x8 af[4], bfr[4];
#pragma unroll
        for (int i = 0; i < 4; i++) {
            af[i]  = *(const bf16x8*)&A [(size_t)(row0 + i*16 + lr) * Kd + k0 + lk];
            bfr[i] = *(const bf16x8*)&Bt[(size_t)(col0 + i*16 + lr) * Kd + k0 + lk];
        }
#pragma unroll
        for (int i = 0; i < 4; i++)
#pragma unroll
            for (int j = 0; j < 4; j++)
                acc[i][j] = __builtin_amdgcn_mfma_f32_16x16x32_bf16(
                    af[i], bfr[j], acc[i][j], 0, 0, 0);
    }
    int crow = (lane >> 4) * 4;
    int ccol = lane & 15;
#pragma unroll
    for (int i = 0; i < 4; i++)
#pragma unroll
        for (int j = 0; j < 4; j++)
#pragma unroll
            for (int r = 0; r < 4; r++) {
                int row = row0 + i*16 + crow + r;
                int col = col0 + j*16 + ccol;
                float v = acc[i][j][r] + bias[col];
                if (BF16OUT)
                    ((short*)Cout)[(size_t)row * N + col] = f2bf(v);
                else
                    ((float*)Cout)[(size_t)row * N + col] = v;
            }
}

// --------------------------- flash MQA attention v2 -------------------------
// Wave owns 32 q-rows (2 row-tiles); 64-key blocks; perfect balance by pairing
// row-block t with 127-t. K read from fused QKV (L2-resident); V from Vt.
static __device__ __forceinline__ f32x4 mfma16(bf16x8 a, bf16x8 b, f32x4 c) {
    return __builtin_amdgcn_mfma_f32_16x16x32_bf16(a, b, c, 0, 0, 0);
}

template <bool MASK>
static __device__ __forceinline__ void attn_step(
    const short* __restrict__ krow0,   // K block base: row stride QKVLD
    const short* __restrict__ vtb,     // Vt block base: row stride S_
    short (*plds)[72],
    const bf16x8 (&qf)[2][4],
    f32x4 (&o)[2][8], float (&m)[2][4], float (&l)[2][4],
    int q0, int key0, int lane)
{
    const int lr = lane & 15, lk = (lane >> 4) * 8;
    const int crow = (lane >> 4) * 4, ccol = lane & 15;
    const float scale = 0.08838834764831845f;  // 1/sqrt(128)

    f32x4 s[2][4] = {};
#pragma unroll
    for (int kk = 0; kk < 4; kk++) {
        bf16x8 kf[4];
#pragma unroll
        for (int kt = 0; kt < 4; kt++)
            kf[kt] = *(const bf16x8*)&krow0[(size_t)(kt*16 + lr) * QKVLD + kk*32 + lk];
#pragma unroll
        for (int i = 0; i < 2; i++)
#pragma unroll
            for (int kt = 0; kt < 4; kt++)
                s[i][kt] = mfma16(qf[i][kk], kf[kt], s[i][kt]);
    }
#pragma unroll
    for (int i = 0; i < 2; i++) {
        float corr[4];
#pragma unroll
        for (int r = 0; r < 4; r++) {
            int qrow = q0 + i*16 + crow + r;
            float v[4];
#pragma unroll
            for (int kt = 0; kt < 4; kt++) {
                v[kt] = s[i][kt][r] * scale;
                if (MASK && key0 + kt*16 + ccol > qrow) v[kt] = -1e30f;
            }
            float mb = fmaxf(fmaxf(v[0], v[1]), fmaxf(v[2], v[3]));
#pragma unroll
            for (int off = 1; off < 16; off <<= 1)
                mb = fmaxf(mb, __shfl_xor(mb, off, 16));
            float mn = fmaxf(m[i][r], mb);
            corr[r] = __expf(m[i][r] - mn);
            m[i][r] = mn;
            float rs = 0.f;
#pragma unroll
            for (int kt = 0; kt < 4; kt++) {
                float e = __expf(v[kt] - mn);
                plds[i*16 + crow + r][kt*16 + ccol] = f2bf(e);
                rs += e;
            }
#pragma unroll
            for (int off = 1; off < 16; off <<= 1)
                rs += __shfl_xor(rs, off, 16);
            l[i][r] = l[i][r] * corr[r] + rs;
        }
#pragma unroll
        for (int j = 0; j < 8; j++)
#pragma unroll
            for (int r = 0; r < 4; r++)
                o[i][j][r] *= corr[r];
    }
    // PV: P (A-layout) from LDS, V^T fragments from global (L2-resident)
#pragma unroll
    for (int ks = 0; ks < 2; ks++) {
        bf16x8 pf[2];
#pragma unroll
        for (int i = 0; i < 2; i++)
            pf[i] = *(const bf16x8*)&plds[i*16 + lr][ks*32 + lk];
#pragma unroll
        for (int j = 0; j < 8; j++) {
            bf16x8 vf = *(const bf16x8*)&vtb[(size_t)(j*16 + lr) * S_ + ks*32 + lk];
#pragma unroll
            for (int i = 0; i < 2; i++)
                o[i][j] = mfma16(pf[i], vf, o[i][j]);
        }
    }
}

__global__ __launch_bounds__(256)
void attn_kernel(const short* __restrict__ QKV, const short* __restrict__ Vt,
                 short* __restrict__ Out) {
    __shared__ __align__(16) short plds_all[4][32][72];
    int wave = threadIdx.x >> 6;
    int lane = threadIdx.x & 63;
    int w = blockIdx.x * 4 + wave;          // 0..2047
    int bh = w & 31;
    int tt = w >> 5;                        // 0..63
    int b = bh >> 4, h = bh & 15;
    short (*plds)[72] = plds_all[wave];
    int lr = lane & 15, lk = (lane >> 4) * 8;
    int crow = (lane >> 4) * 4, ccol = lane & 15;

    const short* qkv_b = QKV + (size_t)b * S_ * QKVLD;
    const short* vtb_b = Vt + (size_t)b * HD_ * S_;
    const short* kb0   = qkv_b + QKDIM_;

#pragma unroll 1
    for (int phase = 0; phase < 2; phase++) {
        int t  = phase == 0 ? (127 - tt) : tt;   // pair long with short
        int q0 = t * 32;
        bf16x8 qf[2][4];
#pragma unroll
        for (int i = 0; i < 2; i++)
#pragma unroll
            for (int kk = 0; kk < 4; kk++)
                qf[i][kk] = *(const bf16x8*)&qkv_b[(size_t)(q0 + i*16 + lr) * QKVLD
                                                   + h*HD_ + kk*32 + lk];
        f32x4 o[2][8] = {};
        float m[2][4], l[2][4];
#pragma unroll
        for (int i = 0; i < 2; i++)
#pragma unroll
            for (int r = 0; r < 4; r++) { m[i][r] = -1e30f; l[i][r] = 0.f; }

        int nb = q0 / 64 + 1;
#pragma unroll 1
        for (int kb = 0; kb < nb - 1; kb++)
            attn_step<false>(kb0 + (size_t)(kb*64) * QKVLD, vtb_b + kb*64,
                             plds, qf, o, m, l, q0, kb*64, lane);
        attn_step<true>(kb0 + (size_t)((nb-1)*64) * QKVLD, vtb_b + (nb-1)*64,
                        plds, qf, o, m, l, q0, (nb-1)*64, lane);

#pragma unroll
        for (int i = 0; i < 2; i++)
#pragma unroll
            for (int j = 0; j < 8; j++)
#pragma unroll
                for (int r = 0; r < 4; r++) {
                    int row = q0 + i*16 + crow + r;
                    Out[(size_t)(b*S_ + row) * QKDIM_ + h*HD_ + j*16 + ccol] =
                        f2bf(o[i][j][r] / l[i][r]);
                }
    }
}

// ------------------------------- launcher -----------------------------------
extern "C" void kernel_launch(void* const* d_in, const int* in_sizes, int n_in,
                              void* d_out, int out_size, void* d_ws, size_t ws_size,
                              hipStream_t stream) {
    (void)in_sizes; (void)n_in; (void)out_size; (void)ws_size;
    const float* x  = (const float*)d_in[0];
    const float* Wq = (const float*)d_in[1];
    const float* bq = (const float*)d_in[2];
    const float* Wk = (const float*)d_in[3];
    const float* bk = (const float*)d_in[4];
    const float* Wv = (const float*)d_in[5];
    const float* bv = (const float*)d_in[6];
    const float* Wo = (const float*)d_in[7];
    const float* bo = (const float*)d_in[8];
    float* out = (float*)d_out;

    char* ws = (char*)d_ws;
    const size_t M = (size_t)B_ * S_;                         // 8192
    short* xb     = (short*)(ws);                             // 33,554,432 B
    short* Wqkv_t = (short*)(ws + 33554432);                  //  9,437,184
    short* Wo_t   = (short*)(ws + 42991616);                  //  8,388,608
    float* bqkv   = (float*)(ws + 51380224);                  //     16,384
    short* QKV    = (short*)(ws + 51396608);                  // 37,748,736
    short* Vtb    = (short*)(ws + 89145344);                  //  2,097,152
    short* attn   = (short*)(ws + 91242496);                  // 33,554,432
    // total: 124,796,928 B

    // casts / transposes / bias concat
    cast_f32_bf16_kernel<<<2048, 256, 0, stream>>>(x, xb, (int)(M * E_ / 4));
    transpose_cast_kernel<<<dim3(E_/32,  E_/32), 256, 0, stream>>>(Wq, Wqkv_t, E_, QKDIM_);
    transpose_cast_kernel<<<dim3(HD_/32, E_/32), 256, 0, stream>>>(Wk, Wqkv_t + (size_t)QKDIM_*E_, E_, HD_);
    transpose_cast_kernel<<<dim3(HD_/32, E_/32), 256, 0, stream>>>(Wv, Wqkv_t + (size_t)(QKDIM_+HD_)*E_, E_, HD_);
    transpose_cast_kernel<<<dim3(E_/32,  E_/32), 256, 0, stream>>>(Wo, Wo_t, QKDIM_, E_);
    concat_bias_kernel<<<9, 256, 0, stream>>>(bq, bk, bv, bqkv);

    // fused QKV projection: [8192,2048] @ [2048,2304] -> [8192,2304]
    gemm_kernel<true><<<dim3(QKVLD/128, M/128), 256, 0, stream>>>(
        xb, Wqkv_t, bqkv, QKV, (int)M, QKVLD, E_);

    // V^T: [B][HD][S] from QKV's V columns
    transpose_v_kernel<<<dim3(HD_/32, S_/32, B_), 256, 0, stream>>>(
        QKV + QKDIM_ + HD_, Vtb, QKVLD);

    // attention: 2048 waves, each handles row-blocks t and 127-t (balanced)
    attn_kernel<<<512, 256, 0, stream>>>(QKV, Vtb, attn);

    // output projection (f32 out)
    gemm_kernel<false><<<dim3(E_/128, M/128), 256, 0, stream>>>(
        attn, Wo_t, bo, out, (int)M, E_, E_);
}

// Round 3
// 1160.835 us; speedup vs baseline: 1.9285x; 1.2708x over previous
//
#include <hip/hip_runtime.h>
#include <hip/hip_bf16.h>

#define B_  2
#define S_  4096
#define E_  2048
#define H_  16
#define HD_ 128
#define QKDIM_ (H_*HD_)   // 2048
#define QKVLD  2304       // fused QKV row stride (2048 Q + 128 K + 128 V)

typedef __attribute__((ext_vector_type(8))) short bf16x8;
typedef __attribute__((ext_vector_type(4))) float f32x4;

static __device__ __forceinline__ short f2bf(float f) {
    unsigned int u = __builtin_bit_cast(unsigned int, f);
    unsigned int r = 0x7FFFu + ((u >> 16) & 1u);
    u += r;
    return (short)(u >> 16);
}

static __device__ __forceinline__ unsigned cvt_pk_bf16(float lo, float hi) {
    unsigned r;
    asm volatile("v_cvt_pk_bf16_f32 %0, %1, %2" : "=v"(r) : "v"(lo), "v"(hi));
    return r;
}

// ---------------- cast f32 -> bf16 (vectorized, grid-stride) ----------------
__global__ void cast_f32_bf16_kernel(const float* __restrict__ in,
                                     short* __restrict__ out, int n4) {
    int stride = gridDim.x * blockDim.x;
    for (int i = blockIdx.x * blockDim.x + threadIdx.x; i < n4; i += stride) {
        float4 v = ((const float4*)in)[i];
        short4 o;
        o.x = f2bf(v.x); o.y = f2bf(v.y); o.z = f2bf(v.z); o.w = f2bf(v.w);
        ((short4*)out)[i] = o;
    }
}

// ------------- transpose + cast: W[K,N] f32  ->  Wt[N,K] bf16 ---------------
__global__ void transpose_cast_kernel(const float* __restrict__ in,
                                      short* __restrict__ out, int K, int N) {
    __shared__ float tile[32][33];
    int nb = blockIdx.x * 32, kb = blockIdx.y * 32;
    int tx = threadIdx.x & 31, ty = threadIdx.x >> 5;   // 256 thr: 8 rows/pass
    for (int r = ty; r < 32; r += 8)
        tile[r][tx] = in[(size_t)(kb + r) * N + nb + tx];
    __syncthreads();
    for (int r = ty; r < 32; r += 8)
        out[(size_t)(nb + r) * K + kb + tx] = f2bf(tile[tx][r]);
}

// ---------------------- concat bias [bq|bk|bv] -> f32[2304] -----------------
__global__ void concat_bias_kernel(const float* __restrict__ bq,
                                   const float* __restrict__ bk,
                                   const float* __restrict__ bv,
                                   float* __restrict__ out) {
    int i = blockIdx.x * 256 + threadIdx.x;
    if (i >= QKVLD) return;
    if (i < QKDIM_)            out[i] = bq[i];
    else if (i < QKDIM_ + HD_) out[i] = bk[i - QKDIM_];
    else                       out[i] = bv[i - QKDIM_ - HD_];
}

// --------- transpose V: QKV[B*S, ld] (V cols) bf16 -> [B][HD][S] bf16 -------
__global__ void transpose_v_kernel(const short* __restrict__ in,
                                   short* __restrict__ out, int ld) {
    __shared__ short tile[32][33];
    int b = blockIdx.z;
    int db = blockIdx.x * 32, sb = blockIdx.y * 32;
    int tx = threadIdx.x & 31, ty = threadIdx.x >> 5;
    for (int r = ty; r < 32; r += 8)
        tile[r][tx] = in[(size_t)(b * S_ + sb + r) * ld + db + tx];
    __syncthreads();
    for (int r = ty; r < 32; r += 8)
        out[((size_t)b * HD_ + db + r) * S_ + sb + tx] = tile[tx][r];
}

// ---------------- GEMM: C[M,N] = A[M,K] @ Bt[N,K]^T + bias[N] ---------------
template <bool BF16OUT>
__global__ __launch_bounds__(256)
void gemm_kernel(const short* __restrict__ A, const short* __restrict__ Bt,
                 const float* __restrict__ bias, void* __restrict__ Cout,
                 int M, int N, int Kd) {
    int wave = threadIdx.x >> 6;
    int lane = threadIdx.x & 63;
    int wr = wave >> 1, wc = wave & 1;
    int row0 = blockIdx.y * 128 + wr * 64;
    int col0 = blockIdx.x * 128 + wc * 64;
    int lr = lane & 15;
    int lk = (lane >> 4) * 8;

    f32x4 acc[4][4] = {};
    for (int k0 = 0; k0 < Kd; k0 += 32) {
        bf16x8 af[4], bfr[4];
#pragma unroll
        for (int i = 0; i < 4; i++) {
            af[i]  = *(const bf16x8*)&A [(size_t)(row0 + i*16 + lr) * Kd + k0 + lk];
            bfr[i] = *(const bf16x8*)&Bt[(size_t)(col0 + i*16 + lr) * Kd + k0 + lk];
        }
#pragma unroll
        for (int i = 0; i < 4; i++)
#pragma unroll
            for (int j = 0; j < 4; j++)
                acc[i][j] = __builtin_amdgcn_mfma_f32_16x16x32_bf16(
                    af[i], bfr[j], acc[i][j], 0, 0, 0);
    }
    int crow = (lane >> 4) * 4;
    int ccol = lane & 15;
#pragma unroll
    for (int i = 0; i < 4; i++)
#pragma unroll
        for (int j = 0; j < 4; j++)
#pragma unroll
            for (int r = 0; r < 4; r++) {
                int row = row0 + i*16 + crow + r;
                int col = col0 + j*16 + ccol;
                float v = acc[i][j][r] + bias[col];
                if (BF16OUT)
                    ((short*)Cout)[(size_t)row * N + col] = f2bf(v);
                else
                    ((float*)Cout)[(size_t)row * N + col] = v;
            }
}

// --------------------------- flash MQA attention v3 -------------------------
// Swapped QK^T: S^T = mfma(K, Q) puts 16 key-scores per lane (q = lane&15) ->
// in-register row reduce (tree + 2 shfl_xor). P packed via cvt_pk + b64 LDS
// writes. V prefetched under softmax. Wave owns 32 q-rows, paired t/127-t.
static __device__ __forceinline__ f32x4 mfma16(bf16x8 a, bf16x8 b, f32x4 c) {
    return __builtin_amdgcn_mfma_f32_16x16x32_bf16(a, b, c, 0, 0, 0);
}

template <bool MASK>
static __device__ __forceinline__ void attn_step(
    const short* __restrict__ krow0,   // K block base: row stride QKVLD
    const short* __restrict__ vtb,     // Vt block base: row stride S_
    short (*plds)[72],
    const bf16x8 (&qf)[2][4],
    f32x4 (&o)[2][8], float (&m)[2], float (&l)[2],
    int q0, int key0, int lane)
{
    const int g = lane >> 4, c = lane & 15;
    const int crow = g * 4;
    const float scale = 0.08838834764831845f;  // 1/sqrt(128)

    // ---- QK^T swapped: s[i][kt] holds S^T[key][q]; lane: q=c, key=kt*16+crow+r
    f32x4 s[2][4] = {};
    __builtin_amdgcn_s_setprio(1);
#pragma unroll
    for (int kk = 0; kk < 4; kk++) {
        bf16x8 kfk[4];
#pragma unroll
        for (int kt = 0; kt < 4; kt++)
            kfk[kt] = *(const bf16x8*)&krow0[(size_t)(kt*16 + c) * QKVLD + kk*32 + g*8];
#pragma unroll
        for (int i = 0; i < 2; i++)
#pragma unroll
            for (int kt = 0; kt < 4; kt++)
                s[i][kt] = mfma16(kfk[kt], qf[i][kk], s[i][kt]);
    }
    __builtin_amdgcn_s_setprio(0);

    // ---- prefetch all V fragments (consumed after softmax)
    bf16x8 vf0[8], vf1[8];
#pragma unroll
    for (int j = 0; j < 8; j++)
        vf0[j] = *(const bf16x8*)&vtb[(size_t)(j*16 + c) * S_ + g*8];
#pragma unroll
    for (int j = 0; j < 8; j++)
        vf1[j] = *(const bf16x8*)&vtb[(size_t)(j*16 + c) * S_ + 32 + g*8];

    // ---- softmax, fully per-lane along keys
    float corrR[2][4];
#pragma unroll
    for (int i = 0; i < 2; i++) {
        float v[16];
#pragma unroll
        for (int kt = 0; kt < 4; kt++)
#pragma unroll
            for (int r = 0; r < 4; r++) {
                float val = s[i][kt][r] * scale;
                if (MASK && key0 + kt*16 + crow + r > q0 + i*16 + c) val = -1e30f;
                v[kt*4 + r] = val;
            }
        float t8[8];
#pragma unroll
        for (int k = 0; k < 8; k++) t8[k] = fmaxf(v[k], v[k+8]);
        float t4a = fmaxf(t8[0], t8[4]), t4b = fmaxf(t8[1], t8[5]);
        float t4c = fmaxf(t8[2], t8[6]), t4d = fmaxf(t8[3], t8[7]);
        float mx = fmaxf(fmaxf(t4a, t4b), fmaxf(t4c, t4d));
        mx = fmaxf(mx, __shfl_xor(mx, 16));
        mx = fmaxf(mx, __shfl_xor(mx, 32));
        float mn = fmaxf(m[i], mx);
        float corr = __expf(m[i] - mn);
        m[i] = mn;
        float e[16];
#pragma unroll
        for (int k = 0; k < 16; k++) e[k] = __expf(v[k] - mn);
        // packed P store: plds[q][key], 4 x ds_write_b64
#pragma unroll
        for (int kt = 0; kt < 4; kt++) {
            uint2 w;
            w.x = cvt_pk_bf16(e[kt*4+0], e[kt*4+1]);
            w.y = cvt_pk_bf16(e[kt*4+2], e[kt*4+3]);
            *(uint2*)&plds[i*16 + c][kt*16 + crow] = w;
        }
        float s8[8];
#pragma unroll
        for (int k = 0; k < 8; k++) s8[k] = e[k] + e[k+8];
        float s4a = s8[0]+s8[4], s4b = s8[1]+s8[5], s4c = s8[2]+s8[6], s4d = s8[3]+s8[7];
        float rs = (s4a + s4b) + (s4c + s4d);
        rs += __shfl_xor(rs, 16);
        rs += __shfl_xor(rs, 32);
        l[i] = l[i] * corr + rs;
        // transpose corr from q=c form to q=crow+r form for o-rescale
#pragma unroll
        for (int r = 0; r < 4; r++) corrR[i][r] = __shfl(corr, crow + r);
    }
#pragma unroll
    for (int i = 0; i < 2; i++)
#pragma unroll
        for (int j = 0; j < 8; j++)
#pragma unroll
            for (int r = 0; r < 4; r++)
                o[i][j][r] *= corrR[i][r];

    // ---- PV: P (A-layout) from LDS, V from prefetched regs
    bf16x8 pf0[2], pf1[2];
#pragma unroll
    for (int i = 0; i < 2; i++)
        pf0[i] = *(const bf16x8*)&plds[i*16 + c][g*8];
#pragma unroll
    for (int i = 0; i < 2; i++)
        pf1[i] = *(const bf16x8*)&plds[i*16 + c][32 + g*8];
    __builtin_amdgcn_s_setprio(1);
#pragma unroll
    for (int j = 0; j < 8; j++)
#pragma unroll
        for (int i = 0; i < 2; i++)
            o[i][j] = mfma16(pf0[i], vf0[j], o[i][j]);
#pragma unroll
    for (int j = 0; j < 8; j++)
#pragma unroll
        for (int i = 0; i < 2; i++)
            o[i][j] = mfma16(pf1[i], vf1[j], o[i][j]);
    __builtin_amdgcn_s_setprio(0);
}

__global__ __launch_bounds__(128)
void attn_kernel(const short* __restrict__ QKV, const short* __restrict__ Vt,
                 short* __restrict__ Out) {
    __shared__ __align__(16) short plds_all[2][32][72];
    int wave = threadIdx.x >> 6;
    int lane = threadIdx.x & 63;
    int w = blockIdx.x * 2 + wave;          // 0..2047
    int bh = w & 31;
    int tt = w >> 5;                        // 0..63
    int b = bh >> 4, h = bh & 15;
    short (*plds)[72] = plds_all[wave];
    int g = lane >> 4, c = lane & 15;
    int crow = g * 4;

    const short* qkv_b = QKV + (size_t)b * S_ * QKVLD;
    const short* vtb_b = Vt + (size_t)b * HD_ * S_;
    const short* kb0   = qkv_b + QKDIM_;

#pragma unroll 1
    for (int phase = 0; phase < 2; phase++) {
        int t  = phase == 0 ? (127 - tt) : tt;   // pair long with short
        int q0 = t * 32;
        // Q fragments (B-operand layout == A-layout addressing from row-major Q)
        bf16x8 qf[2][4];
#pragma unroll
        for (int i = 0; i < 2; i++)
#pragma unroll
            for (int kk = 0; kk < 4; kk++)
                qf[i][kk] = *(const bf16x8*)&qkv_b[(size_t)(q0 + i*16 + c) * QKVLD
                                                   + h*HD_ + kk*32 + g*8];
        f32x4 o[2][8] = {};
        float m[2] = {-1e30f, -1e30f}, l[2] = {0.f, 0.f};

        int nb = q0 / 64 + 1;
#pragma unroll 1
        for (int kb = 0; kb < nb - 1; kb++)
            attn_step<false>(kb0 + (size_t)(kb*64) * QKVLD, vtb_b + kb*64,
                             plds, qf, o, m, l, q0, kb*64, lane);
        attn_step<true>(kb0 + (size_t)((nb-1)*64) * QKVLD, vtb_b + (nb-1)*64,
                        plds, qf, o, m, l, q0, (nb-1)*64, lane);

        // epilogue: transpose l to row form, normalize, store
#pragma unroll
        for (int i = 0; i < 2; i++) {
            float linv[4];
#pragma unroll
            for (int r = 0; r < 4; r++) linv[r] = 1.0f / __shfl(l[i], crow + r);
#pragma unroll
            for (int j = 0; j < 8; j++)
#pragma unroll
                for (int r = 0; r < 4; r++) {
                    int row = q0 + i*16 + crow + r;
                    Out[(size_t)(b*S_ + row) * QKDIM_ + h*HD_ + j*16 + c] =
                        f2bf(o[i][j][r] * linv[r]);
                }
        }
    }
}

// ------------------------------- launcher -----------------------------------
extern "C" void kernel_launch(void* const* d_in, const int* in_sizes, int n_in,
                              void* d_out, int out_size, void* d_ws, size_t ws_size,
                              hipStream_t stream) {
    (void)in_sizes; (void)n_in; (void)out_size; (void)ws_size;
    const float* x  = (const float*)d_in[0];
    const float* Wq = (const float*)d_in[1];
    const float* bq = (const float*)d_in[2];
    const float* Wk = (const float*)d_in[3];
    const float* bk = (const float*)d_in[4];
    const float* Wv = (const float*)d_in[5];
    const float* bv = (const float*)d_in[6];
    const float* Wo = (const float*)d_in[7];
    const float* bo = (const float*)d_in[8];
    float* out = (float*)d_out;

    char* ws = (char*)d_ws;
    const size_t M = (size_t)B_ * S_;                         // 8192
    short* xb     = (short*)(ws);                             // 33,554,432 B
    short* Wqkv_t = (short*)(ws + 33554432);                  //  9,437,184
    short* Wo_t   = (short*)(ws + 42991616);                  //  8,388,608
    float* bqkv   = (float*)(ws + 51380224);                  //     16,384
    short* QKV    = (short*)(ws + 51396608);                  // 37,748,736
    short* Vtb    = (short*)(ws + 89145344);                  //  2,097,152
    short* attn   = (short*)(ws + 91242496);                  // 33,554,432
    // total: 124,796,928 B

    // casts / transposes / bias concat
    cast_f32_bf16_kernel<<<2048, 256, 0, stream>>>(x, xb, (int)(M * E_ / 4));
    transpose_cast_kernel<<<dim3(E_/32,  E_/32), 256, 0, stream>>>(Wq, Wqkv_t, E_, QKDIM_);
    transpose_cast_kernel<<<dim3(HD_/32, E_/32), 256, 0, stream>>>(Wk, Wqkv_t + (size_t)QKDIM_*E_, E_, HD_);
    transpose_cast_kernel<<<dim3(HD_/32, E_/32), 256, 0, stream>>>(Wv, Wqkv_t + (size_t)(QKDIM_+HD_)*E_, E_, HD_);
    transpose_cast_kernel<<<dim3(E_/32,  E_/32), 256, 0, stream>>>(Wo, Wo_t, QKDIM_, E_);
    concat_bias_kernel<<<9, 256, 0, stream>>>(bq, bk, bv, bqkv);

    // fused QKV projection: [8192,2048] @ [2048,2304] -> [8192,2304]
    gemm_kernel<true><<<dim3(QKVLD/128, M/128), 256, 0, stream>>>(
        xb, Wqkv_t, bqkv, QKV, (int)M, QKVLD, E_);

    // V^T: [B][HD][S] from QKV's V columns
    transpose_v_kernel<<<dim3(HD_/32, S_/32, B_), 256, 0, stream>>>(
        QKV + QKDIM_ + HD_, Vtb, QKVLD);

    // attention: 2048 waves (2 per block), each handles row-blocks t and 127-t
    attn_kernel<<<1024, 128, 0, stream>>>(QKV, Vtb, attn);

    // output projection (f32 out)
    gemm_kernel<false><<<dim3(E_/128, M/128), 256, 0, stream>>>(
        attn, Wo_t, bo, out, (int)M, E_, E_);
}

// Round 4
// 944.220 us; speedup vs baseline: 2.3710x; 1.2294x over previous
//
#include <hip/hip_runtime.h>
#include <hip/hip_bf16.h>

#define B_  2
#define S_  4096
#define E_  2048
#define H_  16
#define HD_ 128
#define QKDIM_ (H_*HD_)   // 2048
#define QKVLD  2304       // fused QKV row stride (2048 Q + 128 K + 128 V)

typedef __attribute__((ext_vector_type(8))) short bf16x8;
typedef __attribute__((ext_vector_type(4))) float f32x4;

static __device__ __forceinline__ short f2bf(float f) {
    unsigned int u = __builtin_bit_cast(unsigned int, f);
    unsigned int r = 0x7FFFu + ((u >> 16) & 1u);
    u += r;
    return (short)(u >> 16);
}

static __device__ __forceinline__ unsigned cvt_pk_bf16(float lo, float hi) {
    unsigned r;
    asm volatile("v_cvt_pk_bf16_f32 %0, %1, %2" : "=v"(r) : "v"(lo), "v"(hi));
    return r;
}

static __device__ __forceinline__ void gload_lds16(const short* g, short* l) {
    __builtin_amdgcn_global_load_lds(
        (const __attribute__((address_space(1))) void*)g,
        (__attribute__((address_space(3))) void*)l, 16, 0, 0);
}

// ---------------- cast f32 -> bf16 (vectorized, grid-stride) ----------------
__global__ void cast_f32_bf16_kernel(const float* __restrict__ in,
                                     short* __restrict__ out, int n4) {
    int stride = gridDim.x * blockDim.x;
    for (int i = blockIdx.x * blockDim.x + threadIdx.x; i < n4; i += stride) {
        float4 v = ((const float4*)in)[i];
        short4 o;
        o.x = f2bf(v.x); o.y = f2bf(v.y); o.z = f2bf(v.z); o.w = f2bf(v.w);
        ((short4*)out)[i] = o;
    }
}

// ------------- transpose + cast: W[K,N] f32  ->  Wt[N,K] bf16 ---------------
__global__ void transpose_cast_kernel(const float* __restrict__ in,
                                      short* __restrict__ out, int K, int N) {
    __shared__ float tile[32][33];
    int nb = blockIdx.x * 32, kb = blockIdx.y * 32;
    int tx = threadIdx.x & 31, ty = threadIdx.x >> 5;   // 256 thr: 8 rows/pass
    for (int r = ty; r < 32; r += 8)
        tile[r][tx] = in[(size_t)(kb + r) * N + nb + tx];
    __syncthreads();
    for (int r = ty; r < 32; r += 8)
        out[(size_t)(nb + r) * K + kb + tx] = f2bf(tile[tx][r]);
}

// ---------------------- concat bias [bq|bk|bv] -> f32[2304] -----------------
__global__ void concat_bias_kernel(const float* __restrict__ bq,
                                   const float* __restrict__ bk,
                                   const float* __restrict__ bv,
                                   float* __restrict__ out) {
    int i = blockIdx.x * 256 + threadIdx.x;
    if (i >= QKVLD) return;
    if (i < QKDIM_)            out[i] = bq[i];
    else if (i < QKDIM_ + HD_) out[i] = bk[i - QKDIM_];
    else                       out[i] = bv[i - QKDIM_ - HD_];
}

// --------- transpose V: QKV[B*S, ld] (V cols) bf16 -> [B][HD][S] bf16 -------
__global__ void transpose_v_kernel(const short* __restrict__ in,
                                   short* __restrict__ out, int ld) {
    __shared__ short tile[32][33];
    int b = blockIdx.z;
    int db = blockIdx.x * 32, sb = blockIdx.y * 32;
    int tx = threadIdx.x & 31, ty = threadIdx.x >> 5;
    for (int r = ty; r < 32; r += 8)
        tile[r][tx] = in[(size_t)(b * S_ + sb + r) * ld + db + tx];
    __syncthreads();
    for (int r = ty; r < 32; r += 8)
        out[((size_t)b * HD_ + db + r) * S_ + sb + tx] = tile[tx][r];
}

// ------------- GEMM m97-structure: C = A @ Bt^T + bias, 128x128 tile --------
// BK=32, global_load_lds width=16 staging, linear LDS, 2 barriers per K-step.
template <bool BF16OUT>
__global__ __launch_bounds__(256)
void gemm_lds_kernel(const short* __restrict__ A, const short* __restrict__ Bt,
                     const float* __restrict__ bias, void* __restrict__ Cout,
                     int M, int N, int Kd) {
    __shared__ short smA[128 * 32];
    __shared__ short smB[128 * 32];
    int wave = threadIdx.x >> 6;
    int lane = threadIdx.x & 63;
    int wr = wave >> 1, wc = wave & 1;
    int row_blk = blockIdx.y * 128, col_blk = blockIdx.x * 128;
    int lr = lane & 15;
    int lk = (lane >> 4) * 8;

    // staging: wave stages rows [wave*32, wave*32+32) of each 128x32 tile
    int srow = lane >> 2;              // 0..15
    int scol = (lane & 3) * 8;         // 0,8,16,24
    const short* gA = A  + (size_t)(row_blk + wave*32 + srow) * Kd + scol;
    const short* gB = Bt + (size_t)(col_blk + wave*32 + srow) * Kd + scol;
    short* lA = smA + wave * 32 * 32;  // wave-uniform LDS base
    short* lB = smB + wave * 32 * 32;

    f32x4 acc[4][4] = {};
    for (int k0 = 0; k0 < Kd; k0 += 32) {
        __syncthreads();   // previous tile's reads complete
        gload_lds16(gA + k0,                 lA);
        gload_lds16(gA + k0 + (size_t)16*Kd, lA + 16*32);
        gload_lds16(gB + k0,                 lB);
        gload_lds16(gB + k0 + (size_t)16*Kd, lB + 16*32);
        __syncthreads();   // staging visible (vmcnt drained at barrier)

        bf16x8 af[4], bfr[4];
#pragma unroll
        for (int i = 0; i < 4; i++) {
            af[i]  = *(const bf16x8*)&smA[(wr*64 + i*16 + lr) * 32 + lk];
            bfr[i] = *(const bf16x8*)&smB[(wc*64 + i*16 + lr) * 32 + lk];
        }
#pragma unroll
        for (int i = 0; i < 4; i++)
#pragma unroll
            for (int j = 0; j < 4; j++)
                acc[i][j] = __builtin_amdgcn_mfma_f32_16x16x32_bf16(
                    af[i], bfr[j], acc[i][j], 0, 0, 0);
    }
    int crow = (lane >> 4) * 4;
    int ccol = lane & 15;
#pragma unroll
    for (int i = 0; i < 4; i++)
#pragma unroll
        for (int j = 0; j < 4; j++)
#pragma unroll
            for (int r = 0; r < 4; r++) {
                int row = row_blk + wr*64 + i*16 + crow + r;
                int col = col_blk + wc*64 + j*16 + ccol;
                float v = acc[i][j][r] + bias[col];
                if (BF16OUT)
                    ((short*)Cout)[(size_t)row * N + col] = f2bf(v);
                else
                    ((float*)Cout)[(size_t)row * N + col] = v;
            }
}

// --------------------------- flash MQA attention v4 -------------------------
// One 32-row tile per wave (4096 waves); balance via block composition
// {t,127-t} x 2 heads. Swapped QK^T -> in-register softmax; V prefetch.
static __device__ __forceinline__ f32x4 mfma16(bf16x8 a, bf16x8 b, f32x4 c) {
    return __builtin_amdgcn_mfma_f32_16x16x32_bf16(a, b, c, 0, 0, 0);
}

template <bool MASK>
static __device__ __forceinline__ void attn_step(
    const short* __restrict__ krow0,   // K block base: row stride QKVLD
    const short* __restrict__ vtb,     // Vt block base: row stride S_
    short (*plds)[72],
    const bf16x8 (&qf)[2][4],
    f32x4 (&o)[2][8], float (&m)[2], float (&l)[2],
    int q0, int key0, int lane)
{
    const int g = lane >> 4, c = lane & 15;
    const int crow = g * 4;
    const float scale = 0.08838834764831845f;  // 1/sqrt(128)

    // ---- QK^T swapped: s[i][kt] holds S^T[key][q]; lane: q=c, key=kt*16+crow+r
    f32x4 s[2][4] = {};
    __builtin_amdgcn_s_setprio(1);
#pragma unroll
    for (int kk = 0; kk < 4; kk++) {
        bf16x8 kfk[4];
#pragma unroll
        for (int kt = 0; kt < 4; kt++)
            kfk[kt] = *(const bf16x8*)&krow0[(size_t)(kt*16 + c) * QKVLD + kk*32 + g*8];
#pragma unroll
        for (int i = 0; i < 2; i++)
#pragma unroll
            for (int kt = 0; kt < 4; kt++)
                s[i][kt] = mfma16(kfk[kt], qf[i][kk], s[i][kt]);
    }
    __builtin_amdgcn_s_setprio(0);

    // ---- prefetch all V fragments (consumed after softmax)
    bf16x8 vf0[8], vf1[8];
#pragma unroll
    for (int j = 0; j < 8; j++)
        vf0[j] = *(const bf16x8*)&vtb[(size_t)(j*16 + c) * S_ + g*8];
#pragma unroll
    for (int j = 0; j < 8; j++)
        vf1[j] = *(const bf16x8*)&vtb[(size_t)(j*16 + c) * S_ + 32 + g*8];

    // ---- softmax, fully per-lane along keys
    float corrR[2][4];
#pragma unroll
    for (int i = 0; i < 2; i++) {
        float v[16];
#pragma unroll
        for (int kt = 0; kt < 4; kt++)
#pragma unroll
            for (int r = 0; r < 4; r++) {
                float val = s[i][kt][r] * scale;
                if (MASK && key0 + kt*16 + crow + r > q0 + i*16 + c) val = -1e30f;
                v[kt*4 + r] = val;
            }
        float t8[8];
#pragma unroll
        for (int k = 0; k < 8; k++) t8[k] = fmaxf(v[k], v[k+8]);
        float t4a = fmaxf(t8[0], t8[4]), t4b = fmaxf(t8[1], t8[5]);
        float t4c = fmaxf(t8[2], t8[6]), t4d = fmaxf(t8[3], t8[7]);
        float mx = fmaxf(fmaxf(t4a, t4b), fmaxf(t4c, t4d));
        mx = fmaxf(mx, __shfl_xor(mx, 16));
        mx = fmaxf(mx, __shfl_xor(mx, 32));
        float mn = fmaxf(m[i], mx);
        float corr = __expf(m[i] - mn);
        m[i] = mn;
        float e[16];
#pragma unroll
        for (int k = 0; k < 16; k++) e[k] = __expf(v[k] - mn);
        // packed P store: plds[q][key], 4 x ds_write_b64
#pragma unroll
        for (int kt = 0; kt < 4; kt++) {
            uint2 w;
            w.x = cvt_pk_bf16(e[kt*4+0], e[kt*4+1]);
            w.y = cvt_pk_bf16(e[kt*4+2], e[kt*4+3]);
            *(uint2*)&plds[i*16 + c][kt*16 + crow] = w;
        }
        float s8[8];
#pragma unroll
        for (int k = 0; k < 8; k++) s8[k] = e[k] + e[k+8];
        float s4a = s8[0]+s8[4], s4b = s8[1]+s8[5], s4c = s8[2]+s8[6], s4d = s8[3]+s8[7];
        float rs = (s4a + s4b) + (s4c + s4d);
        rs += __shfl_xor(rs, 16);
        rs += __shfl_xor(rs, 32);
        l[i] = l[i] * corr + rs;
        // transpose corr from q=c form to q=crow+r form for o-rescale
#pragma unroll
        for (int r = 0; r < 4; r++) corrR[i][r] = __shfl(corr, crow + r);
    }
#pragma unroll
    for (int i = 0; i < 2; i++)
#pragma unroll
        for (int j = 0; j < 8; j++)
#pragma unroll
            for (int r = 0; r < 4; r++)
                o[i][j][r] *= corrR[i][r];

    // ---- PV: P (A-layout) from LDS, V from prefetched regs
    bf16x8 pf0[2], pf1[2];
#pragma unroll
    for (int i = 0; i < 2; i++)
        pf0[i] = *(const bf16x8*)&plds[i*16 + c][g*8];
#pragma unroll
    for (int i = 0; i < 2; i++)
        pf1[i] = *(const bf16x8*)&plds[i*16 + c][32 + g*8];
    __builtin_amdgcn_s_setprio(1);
#pragma unroll
    for (int j = 0; j < 8; j++)
#pragma unroll
        for (int i = 0; i < 2; i++)
            o[i][j] = mfma16(pf0[i], vf0[j], o[i][j]);
#pragma unroll
    for (int j = 0; j < 8; j++)
#pragma unroll
        for (int i = 0; i < 2; i++)
            o[i][j] = mfma16(pf1[i], vf1[j], o[i][j]);
    __builtin_amdgcn_s_setprio(0);
}

__global__ __launch_bounds__(256)
void attn_kernel(const short* __restrict__ QKV, const short* __restrict__ Vt,
                 short* __restrict__ Out) {
    __shared__ __align__(16) short plds_all[4][32][72];
    int wave = threadIdx.x >> 6;
    int lane = threadIdx.x & 63;
    int bb = blockIdx.x;                    // 0..1023
    int hh = bb & 7;
    int tt = (bb >> 3) & 63;
    int b  = bb >> 9;
    int h  = hh * 2 + (wave >> 1);
    int t  = (wave & 1) ? (127 - tt) : tt;  // block-balanced composition
    int q0 = t * 32;
    short (*plds)[72] = plds_all[wave];
    int g = lane >> 4, c = lane & 15;
    int crow = g * 4;

    const short* qkv_b = QKV + (size_t)b * S_ * QKVLD;
    const short* vtb_b = Vt + (size_t)b * HD_ * S_;
    const short* kb0   = qkv_b + QKDIM_;

    // Q fragments
    bf16x8 qf[2][4];
#pragma unroll
    for (int i = 0; i < 2; i++)
#pragma unroll
        for (int kk = 0; kk < 4; kk++)
            qf[i][kk] = *(const bf16x8*)&qkv_b[(size_t)(q0 + i*16 + c) * QKVLD
                                               + h*HD_ + kk*32 + g*8];
    f32x4 o[2][8] = {};
    float m[2] = {-1e30f, -1e30f}, l[2] = {0.f, 0.f};

    int nb = q0 / 64 + 1;
#pragma unroll 1
    for (int kb = 0; kb < nb - 1; kb++)
        attn_step<false>(kb0 + (size_t)(kb*64) * QKVLD, vtb_b + kb*64,
                         plds, qf, o, m, l, q0, kb*64, lane);
    attn_step<true>(kb0 + (size_t)((nb-1)*64) * QKVLD, vtb_b + (nb-1)*64,
                    plds, qf, o, m, l, q0, (nb-1)*64, lane);

    // epilogue: transpose l to row form, normalize, store
#pragma unroll
    for (int i = 0; i < 2; i++) {
        float linv[4];
#pragma unroll
        for (int r = 0; r < 4; r++) linv[r] = 1.0f / __shfl(l[i], crow + r);
#pragma unroll
        for (int j = 0; j < 8; j++)
#pragma unroll
            for (int r = 0; r < 4; r++) {
                int row = q0 + i*16 + crow + r;
                Out[(size_t)(b*S_ + row) * QKDIM_ + h*HD_ + j*16 + c] =
                    f2bf(o[i][j][r] * linv[r]);
            }
    }
}

// ------------------------------- launcher -----------------------------------
extern "C" void kernel_launch(void* const* d_in, const int* in_sizes, int n_in,
                              void* d_out, int out_size, void* d_ws, size_t ws_size,
                              hipStream_t stream) {
    (void)in_sizes; (void)n_in; (void)out_size; (void)ws_size;
    const float* x  = (const float*)d_in[0];
    const float* Wq = (const float*)d_in[1];
    const float* bq = (const float*)d_in[2];
    const float* Wk = (const float*)d_in[3];
    const float* bk = (const float*)d_in[4];
    const float* Wv = (const float*)d_in[5];
    const float* bv = (const float*)d_in[6];
    const float* Wo = (const float*)d_in[7];
    const float* bo = (const float*)d_in[8];
    float* out = (float*)d_out;

    char* ws = (char*)d_ws;
    const size_t M = (size_t)B_ * S_;                         // 8192
    short* xb     = (short*)(ws);                             // 33,554,432 B
    short* Wqkv_t = (short*)(ws + 33554432);                  //  9,437,184
    short* Wo_t   = (short*)(ws + 42991616);                  //  8,388,608
    float* bqkv   = (float*)(ws + 51380224);                  //     16,384
    short* QKV    = (short*)(ws + 51396608);                  // 37,748,736
    short* Vtb    = (short*)(ws + 89145344);                  //  2,097,152
    short* attn   = (short*)(ws + 91242496);                  // 33,554,432
    // total: 124,796,928 B

    // casts / transposes / bias concat
    cast_f32_bf16_kernel<<<2048, 256, 0, stream>>>(x, xb, (int)(M * E_ / 4));
    transpose_cast_kernel<<<dim3(E_/32,  E_/32), 256, 0, stream>>>(Wq, Wqkv_t, E_, QKDIM_);
    transpose_cast_kernel<<<dim3(HD_/32, E_/32), 256, 0, stream>>>(Wk, Wqkv_t + (size_t)QKDIM_*E_, E_, HD_);
    transpose_cast_kernel<<<dim3(HD_/32, E_/32), 256, 0, stream>>>(Wv, Wqkv_t + (size_t)(QKDIM_+HD_)*E_, E_, HD_);
    transpose_cast_kernel<<<dim3(E_/32,  E_/32), 256, 0, stream>>>(Wo, Wo_t, QKDIM_, E_);
    concat_bias_kernel<<<9, 256, 0, stream>>>(bq, bk, bv, bqkv);

    // fused QKV projection: [8192,2048] @ [2048,2304] -> [8192,2304]
    gemm_lds_kernel<true><<<dim3(QKVLD/128, M/128), 256, 0, stream>>>(
        xb, Wqkv_t, bqkv, QKV, (int)M, QKVLD, E_);

    // V^T: [B][HD][S] from QKV's V columns
    transpose_v_kernel<<<dim3(HD_/32, S_/32, B_), 256, 0, stream>>>(
        QKV + QKDIM_ + HD_, Vtb, QKVLD);

    // attention: 4096 waves, 4 per block, block-balanced {t,127-t}x2 heads
    attn_kernel<<<1024, 256, 0, stream>>>(QKV, Vtb, attn);

    // output projection (f32 out)
    gemm_lds_kernel<false><<<dim3(E_/128, M/128), 256, 0, stream>>>(
        attn, Wo_t, bo, out, (int)M, E_, E_);
}

// Round 5
// 809.627 us; speedup vs baseline: 2.7651x; 1.1662x over previous
//
#include <hip/hip_runtime.h>
#include <hip/hip_bf16.h>

#define B_  2
#define S_  4096
#define E_  2048
#define H_  16
#define HD_ 128
#define QKDIM_ (H_*HD_)   // 2048
#define QKVLD  2304       // fused QKV row stride (2048 Q + 128 K + 128 V)

typedef __attribute__((ext_vector_type(8))) short bf16x8;
typedef __attribute__((ext_vector_type(4))) float f32x4;

static __device__ __forceinline__ short f2bf(float f) {
    unsigned int u = __builtin_bit_cast(unsigned int, f);
    unsigned int r = 0x7FFFu + ((u >> 16) & 1u);
    u += r;
    return (short)(u >> 16);
}

static __device__ __forceinline__ unsigned cvt_pk_bf16(float lo, float hi) {
    unsigned r;
    asm volatile("v_cvt_pk_bf16_f32 %0, %1, %2" : "=v"(r) : "v"(lo), "v"(hi));
    return r;
}

static __device__ __forceinline__ void gload_lds16(const short* g, short* l) {
    __builtin_amdgcn_global_load_lds(
        (const __attribute__((address_space(1))) void*)g,
        (__attribute__((address_space(3))) void*)l, 16, 0, 0);
}

// ---------------- cast f32 -> bf16 (vectorized, grid-stride) ----------------
__global__ void cast_f32_bf16_kernel(const float* __restrict__ in,
                                     short* __restrict__ out, int n4) {
    int stride = gridDim.x * blockDim.x;
    for (int i = blockIdx.x * blockDim.x + threadIdx.x; i < n4; i += stride) {
        float4 v = ((const float4*)in)[i];
        short4 o;
        o.x = f2bf(v.x); o.y = f2bf(v.y); o.z = f2bf(v.z); o.w = f2bf(v.w);
        ((short4*)out)[i] = o;
    }
}

// ------------- transpose + cast: W[K,N] f32  ->  Wt[N,K] bf16 ---------------
__global__ void transpose_cast_kernel(const float* __restrict__ in,
                                      short* __restrict__ out, int K, int N) {
    __shared__ float tile[32][33];
    int nb = blockIdx.x * 32, kb = blockIdx.y * 32;
    int tx = threadIdx.x & 31, ty = threadIdx.x >> 5;   // 256 thr: 8 rows/pass
    for (int r = ty; r < 32; r += 8)
        tile[r][tx] = in[(size_t)(kb + r) * N + nb + tx];
    __syncthreads();
    for (int r = ty; r < 32; r += 8)
        out[(size_t)(nb + r) * K + kb + tx] = f2bf(tile[tx][r]);
}

// ---------------------- concat bias [bq|bk|bv] -> f32[2304] -----------------
__global__ void concat_bias_kernel(const float* __restrict__ bq,
                                   const float* __restrict__ bk,
                                   const float* __restrict__ bv,
                                   float* __restrict__ out) {
    int i = blockIdx.x * 256 + threadIdx.x;
    if (i >= QKVLD) return;
    if (i < QKDIM_)            out[i] = bq[i];
    else if (i < QKDIM_ + HD_) out[i] = bk[i - QKDIM_];
    else                       out[i] = bv[i - QKDIM_ - HD_];
}

// --------- transpose V: QKV[B*S, ld] (V cols) bf16 -> [B][HD][S] bf16 -------
__global__ void transpose_v_kernel(const short* __restrict__ in,
                                   short* __restrict__ out, int ld) {
    __shared__ short tile[32][33];
    int b = blockIdx.z;
    int db = blockIdx.x * 32, sb = blockIdx.y * 32;
    int tx = threadIdx.x & 31, ty = threadIdx.x >> 5;
    for (int r = ty; r < 32; r += 8)
        tile[r][tx] = in[(size_t)(b * S_ + sb + r) * ld + db + tx];
    __syncthreads();
    for (int r = ty; r < 32; r += 8)
        out[((size_t)b * HD_ + db + r) * S_ + sb + tx] = tile[tx][r];
}

// ------------- GEMM m97-structure: C = A @ Bt^T + bias, 128x128 tile --------
template <bool BF16OUT>
__global__ __launch_bounds__(256)
void gemm_lds_kernel(const short* __restrict__ A, const short* __restrict__ Bt,
                     const float* __restrict__ bias, void* __restrict__ Cout,
                     int M, int N, int Kd) {
    __shared__ short smA[128 * 32];
    __shared__ short smB[128 * 32];
    int wave = threadIdx.x >> 6;
    int lane = threadIdx.x & 63;
    int wr = wave >> 1, wc = wave & 1;
    int row_blk = blockIdx.y * 128, col_blk = blockIdx.x * 128;
    int lr = lane & 15;
    int lk = (lane >> 4) * 8;

    int srow = lane >> 2;              // 0..15
    int scol = (lane & 3) * 8;         // 0,8,16,24
    const short* gA = A  + (size_t)(row_blk + wave*32 + srow) * Kd + scol;
    const short* gB = Bt + (size_t)(col_blk + wave*32 + srow) * Kd + scol;
    short* lA = smA + wave * 32 * 32;
    short* lB = smB + wave * 32 * 32;

    f32x4 acc[4][4] = {};
    for (int k0 = 0; k0 < Kd; k0 += 32) {
        __syncthreads();
        gload_lds16(gA + k0,                 lA);
        gload_lds16(gA + k0 + (size_t)16*Kd, lA + 16*32);
        gload_lds16(gB + k0,                 lB);
        gload_lds16(gB + k0 + (size_t)16*Kd, lB + 16*32);
        __syncthreads();

        bf16x8 af[4], bfr[4];
#pragma unroll
        for (int i = 0; i < 4; i++) {
            af[i]  = *(const bf16x8*)&smA[(wr*64 + i*16 + lr) * 32 + lk];
            bfr[i] = *(const bf16x8*)&smB[(wc*64 + i*16 + lr) * 32 + lk];
        }
#pragma unroll
        for (int i = 0; i < 4; i++)
#pragma unroll
            for (int j = 0; j < 4; j++)
                acc[i][j] = __builtin_amdgcn_mfma_f32_16x16x32_bf16(
                    af[i], bfr[j], acc[i][j], 0, 0, 0);
    }
    int crow = (lane >> 4) * 4;
    int ccol = lane & 15;
#pragma unroll
    for (int i = 0; i < 4; i++)
#pragma unroll
        for (int j = 0; j < 4; j++)
#pragma unroll
            for (int r = 0; r < 4; r++) {
                int row = row_blk + wr*64 + i*16 + crow + r;
                int col = col_blk + wc*64 + j*16 + ccol;
                float v = acc[i][j][r] + bias[col];
                if (BF16OUT)
                    ((short*)Cout)[(size_t)row * N + col] = f2bf(v);
                else
                    ((float*)Cout)[(size_t)row * N + col] = v;
            }
}

// --------------------------- flash MQA attention v5 -------------------------
// Block = 8 waves = 8 heads, same (b, tile-pair {127-tt, tt}) -> uniform 65
// steps/wave, 256 blocks = 1/CU static. K tile (64x128) double-buffered in
// LDS, XOR-swizzled, staged via global_load_lds once per block-step. Swapped
// QK^T in-register softmax; V prefetched from global; P via per-wave LDS.
static __device__ __forceinline__ f32x4 mfma16(bf16x8 a, bf16x8 b, f32x4 c) {
    return __builtin_amdgcn_mfma_f32_16x16x32_bf16(a, b, c, 0, 0, 0);
}

template <bool MASK>
static __device__ __forceinline__ void attn_step(
    const short* __restrict__ ks,      // LDS K tile, swizzled [64][16 chunks]
    const short* __restrict__ vtb,     // Vt block base: row stride S_
    short (*pw)[72],
    const bf16x8 (&qf)[2][4],
    f32x4 (&o)[2][8], float (&m)[2], float (&l)[2],
    int q0, int key0, int lane)
{
    const int g = lane >> 4, c = lane & 15;
    const int crow = g * 4;
    const float scale = 0.08838834764831845f;  // 1/sqrt(128)

    // ---- prefetch all V fragments (global, consumed after softmax)
    bf16x8 vf0[8], vf1[8];
#pragma unroll
    for (int j = 0; j < 8; j++)
        vf0[j] = *(const bf16x8*)&vtb[(size_t)(j*16 + c) * S_ + g*8];
#pragma unroll
    for (int j = 0; j < 8; j++)
        vf1[j] = *(const bf16x8*)&vtb[(size_t)(j*16 + c) * S_ + 32 + g*8];

    // ---- QK^T swapped, K from swizzled LDS
    f32x4 s[2][4] = {};
    __builtin_amdgcn_s_setprio(1);
#pragma unroll
    for (int kk = 0; kk < 4; kk++) {
        bf16x8 kfk[4];
#pragma unroll
        for (int kt = 0; kt < 4; kt++)
            kfk[kt] = *(const bf16x8*)&ks[(kt*16 + c)*128 + (((kk*4 + g) ^ (c & 7))*8)];
#pragma unroll
        for (int i = 0; i < 2; i++)
#pragma unroll
            for (int kt = 0; kt < 4; kt++)
                s[i][kt] = mfma16(kfk[kt], qf[i][kk], s[i][kt]);
    }
    __builtin_amdgcn_s_setprio(0);

    // ---- per i-tile: softmax (in-register along keys) -> P -> PV
#pragma unroll
    for (int i = 0; i < 2; i++) {
        float v[16];
#pragma unroll
        for (int kt = 0; kt < 4; kt++)
#pragma unroll
            for (int r = 0; r < 4; r++) {
                float val = s[i][kt][r] * scale;
                if (MASK && key0 + kt*16 + crow + r > q0 + i*16 + c) val = -1e30f;
                v[kt*4 + r] = val;
            }
        float t8[8];
#pragma unroll
        for (int k = 0; k < 8; k++) t8[k] = fmaxf(v[k], v[k+8]);
        float t4a = fmaxf(t8[0], t8[4]), t4b = fmaxf(t8[1], t8[5]);
        float t4c = fmaxf(t8[2], t8[6]), t4d = fmaxf(t8[3], t8[7]);
        float mx = fmaxf(fmaxf(t4a, t4b), fmaxf(t4c, t4d));
        mx = fmaxf(mx, __shfl_xor(mx, 16));
        mx = fmaxf(mx, __shfl_xor(mx, 32));
        float mn = fmaxf(m[i], mx);
        float corr = __expf(m[i] - mn);
        m[i] = mn;
        float e[16];
#pragma unroll
        for (int k = 0; k < 16; k++) e[k] = __expf(v[k] - mn);
#pragma unroll
        for (int kt = 0; kt < 4; kt++) {
            uint2 w;
            w.x = cvt_pk_bf16(e[kt*4+0], e[kt*4+1]);
            w.y = cvt_pk_bf16(e[kt*4+2], e[kt*4+3]);
            *(uint2*)&pw[c][kt*16 + crow] = w;
        }
        float s8[8];
#pragma unroll
        for (int k = 0; k < 8; k++) s8[k] = e[k] + e[k+8];
        float rs = ((s8[0]+s8[4]) + (s8[1]+s8[5])) + ((s8[2]+s8[6]) + (s8[3]+s8[7]));
        rs += __shfl_xor(rs, 16);
        rs += __shfl_xor(rs, 32);
        l[i] = l[i] * corr + rs;
        float corrR[4];
#pragma unroll
        for (int r = 0; r < 4; r++) corrR[r] = __shfl(corr, crow + r);
#pragma unroll
        for (int j = 0; j < 8; j++)
#pragma unroll
            for (int r = 0; r < 4; r++)
                o[i][j][r] *= corrR[r];

        bf16x8 pf0 = *(const bf16x8*)&pw[c][g*8];
        bf16x8 pf1 = *(const bf16x8*)&pw[c][32 + g*8];
        __builtin_amdgcn_s_setprio(1);
#pragma unroll
        for (int j = 0; j < 8; j++)
            o[i][j] = mfma16(pf0, vf0[j], o[i][j]);
#pragma unroll
        for (int j = 0; j < 8; j++)
            o[i][j] = mfma16(pf1, vf1[j], o[i][j]);
        __builtin_amdgcn_s_setprio(0);
    }
}

__global__ __launch_bounds__(512)
void attn_kernel(const short* __restrict__ QKV, const short* __restrict__ Vt,
                 short* __restrict__ Out) {
    __shared__ __align__(16) short ksm[2][64 * 128];     // 2 x 16 KB
    __shared__ __align__(16) short plds_all[8][16][72];  // 18 KB
    int wave = threadIdx.x >> 6;
    int lane = threadIdx.x & 63;
    int bb = blockIdx.x;                 // 0..255
    int tt = bb & 63;
    int hg = (bb >> 6) & 1;
    int b  = bb >> 7;
    int h  = hg * 8 + wave;
    short (*pw)[72] = plds_all[wave];
    int g = lane >> 4, c = lane & 15;
    int crow = g * 4;

    const short* qkv_b = QKV + (size_t)b * S_ * QKVLD;
    const short* vtb_b = Vt + (size_t)b * HD_ * S_;
    const short* kb0   = qkv_b + QKDIM_;

    // K staging: this thread's 2 chunks (LDS chunk = wave*128 + q*64 + lane)
    int row0s = wave*8 + (lane >> 4);          // q=0: rows wave*8+0..3  (lane>>4: 0..3)
    // recompute properly inside the lambda below.

    auto stage = [&](int buf, int key0) {
#pragma unroll
        for (int q = 0; q < 2; q++) {
            int ci  = wave*128 + q*64 + lane;
            int row = ci >> 4;                  // 0..63
            int cc  = (ci & 15) ^ (row & 7);    // inverse-swizzled source chunk
            gload_lds16(kb0 + (size_t)(key0 + row) * QKVLD + cc*8,
                        &ksm[buf][(wave*128 + q*64) * 8]);
        }
    };
    (void)row0s;

#pragma unroll 1
    for (int phase = 0; phase < 2; phase++) {
        int t  = phase ? tt : (127 - tt);       // within-wave pairing: uniform
        int q0 = t * 32;
        bf16x8 qf[2][4];
#pragma unroll
        for (int i = 0; i < 2; i++)
#pragma unroll
            for (int kk = 0; kk < 4; kk++)
                qf[i][kk] = *(const bf16x8*)&qkv_b[(size_t)(q0 + i*16 + c) * QKVLD
                                                   + h*HD_ + kk*32 + g*8];
        f32x4 o[2][8] = {};
        float m[2] = {-1e30f, -1e30f}, l[2] = {0.f, 0.f};

        int nb = q0 / 64 + 1;
        int cur = 0;
        __syncthreads();                        // WAR guard across phases
        stage(0, 0);
#pragma unroll 1
        for (int kb = 0; kb < nb; kb++) {
            __syncthreads();                    // drains vmcnt: ksm[cur] ready
            if (kb + 1 < nb) stage(cur ^ 1, (kb + 1) * 64);
            if (kb == nb - 1)
                attn_step<true >(ksm[cur], vtb_b + kb*64, pw, qf, o, m, l, q0, kb*64, lane);
            else
                attn_step<false>(ksm[cur], vtb_b + kb*64, pw, qf, o, m, l, q0, kb*64, lane);
            cur ^= 1;
        }

        // epilogue: transpose l to row form, normalize, store
#pragma unroll
        for (int i = 0; i < 2; i++) {
            float linv[4];
#pragma unroll
            for (int r = 0; r < 4; r++) linv[r] = 1.0f / __shfl(l[i], crow + r);
#pragma unroll
            for (int j = 0; j < 8; j++)
#pragma unroll
                for (int r = 0; r < 4; r++) {
                    int row = q0 + i*16 + crow + r;
                    Out[(size_t)(b*S_ + row) * QKDIM_ + h*HD_ + j*16 + c] =
                        f2bf(o[i][j][r] * linv[r]);
                }
        }
    }
}

// ------------------------------- launcher -----------------------------------
extern "C" void kernel_launch(void* const* d_in, const int* in_sizes, int n_in,
                              void* d_out, int out_size, void* d_ws, size_t ws_size,
                              hipStream_t stream) {
    (void)in_sizes; (void)n_in; (void)out_size; (void)ws_size;
    const float* x  = (const float*)d_in[0];
    const float* Wq = (const float*)d_in[1];
    const float* bq = (const float*)d_in[2];
    const float* Wk = (const float*)d_in[3];
    const float* bk = (const float*)d_in[4];
    const float* Wv = (const float*)d_in[5];
    const float* bv = (const float*)d_in[6];
    const float* Wo = (const float*)d_in[7];
    const float* bo = (const float*)d_in[8];
    float* out = (float*)d_out;

    char* ws = (char*)d_ws;
    const size_t M = (size_t)B_ * S_;                         // 8192
    short* xb     = (short*)(ws);                             // 33,554,432 B
    short* Wqkv_t = (short*)(ws + 33554432);                  //  9,437,184
    short* Wo_t   = (short*)(ws + 42991616);                  //  8,388,608
    float* bqkv   = (float*)(ws + 51380224);                  //     16,384
    short* QKV    = (short*)(ws + 51396608);                  // 37,748,736
    short* Vtb    = (short*)(ws + 89145344);                  //  2,097,152
    short* attn   = (short*)(ws + 91242496);                  // 33,554,432
    // total: 124,796,928 B

    // casts / transposes / bias concat
    cast_f32_bf16_kernel<<<2048, 256, 0, stream>>>(x, xb, (int)(M * E_ / 4));
    transpose_cast_kernel<<<dim3(E_/32,  E_/32), 256, 0, stream>>>(Wq, Wqkv_t, E_, QKDIM_);
    transpose_cast_kernel<<<dim3(HD_/32, E_/32), 256, 0, stream>>>(Wk, Wqkv_t + (size_t)QKDIM_*E_, E_, HD_);
    transpose_cast_kernel<<<dim3(HD_/32, E_/32), 256, 0, stream>>>(Wv, Wqkv_t + (size_t)(QKDIM_+HD_)*E_, E_, HD_);
    transpose_cast_kernel<<<dim3(E_/32,  E_/32), 256, 0, stream>>>(Wo, Wo_t, QKDIM_, E_);
    concat_bias_kernel<<<9, 256, 0, stream>>>(bq, bk, bv, bqkv);

    // fused QKV projection: [8192,2048] @ [2048,2304] -> [8192,2304]
    gemm_lds_kernel<true><<<dim3(QKVLD/128, M/128), 256, 0, stream>>>(
        xb, Wqkv_t, bqkv, QKV, (int)M, QKVLD, E_);

    // V^T: [B][HD][S] from QKV's V columns
    transpose_v_kernel<<<dim3(HD_/32, S_/32, B_), 256, 0, stream>>>(
        QKV + QKDIM_ + HD_, Vtb, QKVLD);

    // attention: 256 blocks x 8 waves (8 heads sharing K via LDS), uniform work
    attn_kernel<<<256, 512, 0, stream>>>(QKV, Vtb, attn);

    // output projection (f32 out)
    gemm_lds_kernel<false><<<dim3(E_/128, M/128), 256, 0, stream>>>(
        attn, Wo_t, bo, out, (int)M, E_, E_);
}

// Round 6
// 804.766 us; speedup vs baseline: 2.7818x; 1.0060x over previous
//
#include <hip/hip_runtime.h>
#include <hip/hip_bf16.h>

#define B_  2
#define S_  4096
#define E_  2048
#define H_  16
#define HD_ 128
#define QKDIM_ (H_*HD_)   // 2048
#define QKVLD  2304       // fused QKV row stride (2048 Q + 128 K + 128 V)

typedef __attribute__((ext_vector_type(8))) short bf16x8;
typedef __attribute__((ext_vector_type(4))) float f32x4;

static __device__ __forceinline__ short f2bf(float f) {
    unsigned int u = __builtin_bit_cast(unsigned int, f);
    unsigned int r = 0x7FFFu + ((u >> 16) & 1u);
    u += r;
    return (short)(u >> 16);
}

static __device__ __forceinline__ unsigned cvt_pk_bf16(float lo, float hi) {
    unsigned r;
    asm volatile("v_cvt_pk_bf16_f32 %0, %1, %2" : "=v"(r) : "v"(lo), "v"(hi));
    return r;
}

static __device__ __forceinline__ void gload_lds16(const short* g, short* l) {
    __builtin_amdgcn_global_load_lds(
        (const __attribute__((address_space(1))) void*)g,
        (__attribute__((address_space(3))) void*)l, 16, 0, 0);
}

// ---------------- cast f32 -> bf16 (vectorized, grid-stride) ----------------
__global__ void cast_f32_bf16_kernel(const float* __restrict__ in,
                                     short* __restrict__ out, int n4) {
    int stride = gridDim.x * blockDim.x;
    for (int i = blockIdx.x * blockDim.x + threadIdx.x; i < n4; i += stride) {
        float4 v = ((const float4*)in)[i];
        short4 o;
        o.x = f2bf(v.x); o.y = f2bf(v.y); o.z = f2bf(v.z); o.w = f2bf(v.w);
        ((short4*)out)[i] = o;
    }
}

// ------------- transpose + cast: W[K,N] f32  ->  Wt[N,K] bf16 ---------------
__global__ void transpose_cast_kernel(const float* __restrict__ in,
                                      short* __restrict__ out, int K, int N) {
    __shared__ float tile[32][33];
    int nb = blockIdx.x * 32, kb = blockIdx.y * 32;
    int tx = threadIdx.x & 31, ty = threadIdx.x >> 5;   // 256 thr: 8 rows/pass
    for (int r = ty; r < 32; r += 8)
        tile[r][tx] = in[(size_t)(kb + r) * N + nb + tx];
    __syncthreads();
    for (int r = ty; r < 32; r += 8)
        out[(size_t)(nb + r) * K + kb + tx] = f2bf(tile[tx][r]);
}

// ---------------------- concat bias [bq|bk|bv] -> f32[2304] -----------------
__global__ void concat_bias_kernel(const float* __restrict__ bq,
                                   const float* __restrict__ bk,
                                   const float* __restrict__ bv,
                                   float* __restrict__ out) {
    int i = blockIdx.x * 256 + threadIdx.x;
    if (i >= QKVLD) return;
    if (i < QKDIM_)            out[i] = bq[i];
    else if (i < QKDIM_ + HD_) out[i] = bk[i - QKDIM_];
    else                       out[i] = bv[i - QKDIM_ - HD_];
}

// --------- transpose V: QKV[B*S, ld] (V cols) bf16 -> [B][HD][S] bf16 -------
__global__ void transpose_v_kernel(const short* __restrict__ in,
                                   short* __restrict__ out, int ld) {
    __shared__ short tile[32][33];
    int b = blockIdx.z;
    int db = blockIdx.x * 32, sb = blockIdx.y * 32;
    int tx = threadIdx.x & 31, ty = threadIdx.x >> 5;
    for (int r = ty; r < 32; r += 8)
        tile[r][tx] = in[(size_t)(b * S_ + sb + r) * ld + db + tx];
    __syncthreads();
    for (int r = ty; r < 32; r += 8)
        out[((size_t)b * HD_ + db + r) * S_ + sb + tx] = tile[tx][r];
}

// ------------- GEMM m97-structure: C = A @ Bt^T + bias, 128x128 tile --------
template <bool BF16OUT>
__global__ __launch_bounds__(256)
void gemm_lds_kernel(const short* __restrict__ A, const short* __restrict__ Bt,
                     const float* __restrict__ bias, void* __restrict__ Cout,
                     int M, int N, int Kd) {
    __shared__ short smA[128 * 32];
    __shared__ short smB[128 * 32];
    int wave = threadIdx.x >> 6;
    int lane = threadIdx.x & 63;
    int wr = wave >> 1, wc = wave & 1;
    int row_blk = blockIdx.y * 128, col_blk = blockIdx.x * 128;
    int lr = lane & 15;
    int lk = (lane >> 4) * 8;

    int srow = lane >> 2;              // 0..15
    int scol = (lane & 3) * 8;         // 0,8,16,24
    const short* gA = A  + (size_t)(row_blk + wave*32 + srow) * Kd + scol;
    const short* gB = Bt + (size_t)(col_blk + wave*32 + srow) * Kd + scol;
    short* lA = smA + wave * 32 * 32;
    short* lB = smB + wave * 32 * 32;

    f32x4 acc[4][4] = {};
    for (int k0 = 0; k0 < Kd; k0 += 32) {
        __syncthreads();
        gload_lds16(gA + k0,                 lA);
        gload_lds16(gA + k0 + (size_t)16*Kd, lA + 16*32);
        gload_lds16(gB + k0,                 lB);
        gload_lds16(gB + k0 + (size_t)16*Kd, lB + 16*32);
        __syncthreads();

        bf16x8 af[4], bfr[4];
#pragma unroll
        for (int i = 0; i < 4; i++) {
            af[i]  = *(const bf16x8*)&smA[(wr*64 + i*16 + lr) * 32 + lk];
            bfr[i] = *(const bf16x8*)&smB[(wc*64 + i*16 + lr) * 32 + lk];
        }
#pragma unroll
        for (int i = 0; i < 4; i++)
#pragma unroll
            for (int j = 0; j < 4; j++)
                acc[i][j] = __builtin_amdgcn_mfma_f32_16x16x32_bf16(
                    af[i], bfr[j], acc[i][j], 0, 0, 0);
    }
    int crow = (lane >> 4) * 4;
    int ccol = lane & 15;
#pragma unroll
    for (int i = 0; i < 4; i++)
#pragma unroll
        for (int j = 0; j < 4; j++)
#pragma unroll
            for (int r = 0; r < 4; r++) {
                int row = row_blk + wr*64 + i*16 + crow + r;
                int col = col_blk + wc*64 + j*16 + ccol;
                float v = acc[i][j][r] + bias[col];
                if (BF16OUT)
                    ((short*)Cout)[(size_t)row * N + col] = f2bf(v);
                else
                    ((float*)Cout)[(size_t)row * N + col] = v;
            }
}

// --------------------------- flash MQA attention v6 -------------------------
// v5 + launch_bounds(512,2): 2 waves/SIMD min -> 256-VGPR cap, no scratch
// spill (v5's 128-VGPR budget caused 157MB of spill writes). V1-half prefetch
// moved after QK MFMAs to shave peak pressure.
static __device__ __forceinline__ f32x4 mfma16(bf16x8 a, bf16x8 b, f32x4 c) {
    return __builtin_amdgcn_mfma_f32_16x16x32_bf16(a, b, c, 0, 0, 0);
}

template <bool MASK>
static __device__ __forceinline__ void attn_step(
    const short* __restrict__ ks,      // LDS K tile, swizzled [64][16 chunks]
    const short* __restrict__ vtb,     // Vt block base: row stride S_
    short (*pw)[72],
    const bf16x8 (&qf)[2][4],
    f32x4 (&o)[2][8], float (&m)[2], float (&l)[2],
    int q0, int key0, int lane)
{
    const int g = lane >> 4, c = lane & 15;
    const int crow = g * 4;
    const float scale = 0.08838834764831845f;  // 1/sqrt(128)

    // ---- prefetch V first half (global; consumed after softmax)
    bf16x8 vf0[8];
#pragma unroll
    for (int j = 0; j < 8; j++)
        vf0[j] = *(const bf16x8*)&vtb[(size_t)(j*16 + c) * S_ + g*8];

    // ---- QK^T swapped, K from swizzled LDS
    f32x4 s[2][4] = {};
    __builtin_amdgcn_s_setprio(1);
#pragma unroll
    for (int kk = 0; kk < 4; kk++) {
        bf16x8 kfk[4];
#pragma unroll
        for (int kt = 0; kt < 4; kt++)
            kfk[kt] = *(const bf16x8*)&ks[(kt*16 + c)*128 + (((kk*4 + g) ^ (c & 7))*8)];
#pragma unroll
        for (int i = 0; i < 2; i++)
#pragma unroll
            for (int kt = 0; kt < 4; kt++)
                s[i][kt] = mfma16(kfk[kt], qf[i][kk], s[i][kt]);
    }
    __builtin_amdgcn_s_setprio(0);

    // ---- prefetch V second half (hides under softmax)
    bf16x8 vf1[8];
#pragma unroll
    for (int j = 0; j < 8; j++)
        vf1[j] = *(const bf16x8*)&vtb[(size_t)(j*16 + c) * S_ + 32 + g*8];

    // ---- per i-tile: softmax (in-register along keys) -> P -> PV
#pragma unroll
    for (int i = 0; i < 2; i++) {
        float v[16];
#pragma unroll
        for (int kt = 0; kt < 4; kt++)
#pragma unroll
            for (int r = 0; r < 4; r++) {
                float val = s[i][kt][r] * scale;
                if (MASK && key0 + kt*16 + crow + r > q0 + i*16 + c) val = -1e30f;
                v[kt*4 + r] = val;
            }
        float t8[8];
#pragma unroll
        for (int k = 0; k < 8; k++) t8[k] = fmaxf(v[k], v[k+8]);
        float t4a = fmaxf(t8[0], t8[4]), t4b = fmaxf(t8[1], t8[5]);
        float t4c = fmaxf(t8[2], t8[6]), t4d = fmaxf(t8[3], t8[7]);
        float mx = fmaxf(fmaxf(t4a, t4b), fmaxf(t4c, t4d));
        mx = fmaxf(mx, __shfl_xor(mx, 16));
        mx = fmaxf(mx, __shfl_xor(mx, 32));
        float mn = fmaxf(m[i], mx);
        float corr = __expf(m[i] - mn);
        m[i] = mn;
        float e[16];
#pragma unroll
        for (int k = 0; k < 16; k++) e[k] = __expf(v[k] - mn);
#pragma unroll
        for (int kt = 0; kt < 4; kt++) {
            uint2 w;
            w.x = cvt_pk_bf16(e[kt*4+0], e[kt*4+1]);
            w.y = cvt_pk_bf16(e[kt*4+2], e[kt*4+3]);
            *(uint2*)&pw[c][kt*16 + crow] = w;
        }
        float s8[8];
#pragma unroll
        for (int k = 0; k < 8; k++) s8[k] = e[k] + e[k+8];
        float rs = ((s8[0]+s8[4]) + (s8[1]+s8[5])) + ((s8[2]+s8[6]) + (s8[3]+s8[7]));
        rs += __shfl_xor(rs, 16);
        rs += __shfl_xor(rs, 32);
        l[i] = l[i] * corr + rs;
        float corrR[4];
#pragma unroll
        for (int r = 0; r < 4; r++) corrR[r] = __shfl(corr, crow + r);
#pragma unroll
        for (int j = 0; j < 8; j++)
#pragma unroll
            for (int r = 0; r < 4; r++)
                o[i][j][r] *= corrR[r];

        bf16x8 pf0 = *(const bf16x8*)&pw[c][g*8];
        bf16x8 pf1 = *(const bf16x8*)&pw[c][32 + g*8];
        __builtin_amdgcn_s_setprio(1);
#pragma unroll
        for (int j = 0; j < 8; j++)
            o[i][j] = mfma16(pf0, vf0[j], o[i][j]);
#pragma unroll
        for (int j = 0; j < 8; j++)
            o[i][j] = mfma16(pf1, vf1[j], o[i][j]);
        __builtin_amdgcn_s_setprio(0);
    }
}

__global__ __launch_bounds__(512, 2)
void attn_kernel(const short* __restrict__ QKV, const short* __restrict__ Vt,
                 short* __restrict__ Out) {
    __shared__ __align__(16) short ksm[2][64 * 128];     // 2 x 16 KB
    __shared__ __align__(16) short plds_all[8][16][72];  // 18 KB
    int wave = threadIdx.x >> 6;
    int lane = threadIdx.x & 63;
    int bb = blockIdx.x;                 // 0..255
    int tt = bb & 63;
    int hg = (bb >> 6) & 1;
    int b  = bb >> 7;
    int h  = hg * 8 + wave;
    short (*pw)[72] = plds_all[wave];
    int g = lane >> 4, c = lane & 15;
    int crow = g * 4;

    const short* qkv_b = QKV + (size_t)b * S_ * QKVLD;
    const short* vtb_b = Vt + (size_t)b * HD_ * S_;
    const short* kb0   = qkv_b + QKDIM_;

    auto stage = [&](int buf, int key0) {
#pragma unroll
        for (int q = 0; q < 2; q++) {
            int ci  = wave*128 + q*64 + lane;
            int row = ci >> 4;                  // 0..63
            int cc  = (ci & 15) ^ (row & 7);    // inverse-swizzled source chunk
            gload_lds16(kb0 + (size_t)(key0 + row) * QKVLD + cc*8,
                        &ksm[buf][(wave*128 + q*64) * 8]);
        }
    };

#pragma unroll 1
    for (int phase = 0; phase < 2; phase++) {
        int t  = phase ? tt : (127 - tt);       // within-wave pairing: uniform
        int q0 = t * 32;
        bf16x8 qf[2][4];
#pragma unroll
        for (int i = 0; i < 2; i++)
#pragma unroll
            for (int kk = 0; kk < 4; kk++)
                qf[i][kk] = *(const bf16x8*)&qkv_b[(size_t)(q0 + i*16 + c) * QKVLD
                                                   + h*HD_ + kk*32 + g*8];
        f32x4 o[2][8] = {};
        float m[2] = {-1e30f, -1e30f}, l[2] = {0.f, 0.f};

        int nb = q0 / 64 + 1;
        int cur = 0;
        __syncthreads();                        // WAR guard across phases
        stage(0, 0);
#pragma unroll 1
        for (int kb = 0; kb < nb; kb++) {
            __syncthreads();                    // drains vmcnt: ksm[cur] ready
            if (kb + 1 < nb) stage(cur ^ 1, (kb + 1) * 64);
            if (kb == nb - 1)
                attn_step<true >(ksm[cur], vtb_b + kb*64, pw, qf, o, m, l, q0, kb*64, lane);
            else
                attn_step<false>(ksm[cur], vtb_b + kb*64, pw, qf, o, m, l, q0, kb*64, lane);
            cur ^= 1;
        }

        // epilogue: transpose l to row form, normalize, store
#pragma unroll
        for (int i = 0; i < 2; i++) {
            float linv[4];
#pragma unroll
            for (int r = 0; r < 4; r++) linv[r] = 1.0f / __shfl(l[i], crow + r);
#pragma unroll
            for (int j = 0; j < 8; j++)
#pragma unroll
                for (int r = 0; r < 4; r++) {
                    int row = q0 + i*16 + crow + r;
                    Out[(size_t)(b*S_ + row) * QKDIM_ + h*HD_ + j*16 + c] =
                        f2bf(o[i][j][r] * linv[r]);
                }
        }
    }
}

// ------------------------------- launcher -----------------------------------
extern "C" void kernel_launch(void* const* d_in, const int* in_sizes, int n_in,
                              void* d_out, int out_size, void* d_ws, size_t ws_size,
                              hipStream_t stream) {
    (void)in_sizes; (void)n_in; (void)out_size; (void)ws_size;
    const float* x  = (const float*)d_in[0];
    const float* Wq = (const float*)d_in[1];
    const float* bq = (const float*)d_in[2];
    const float* Wk = (const float*)d_in[3];
    const float* bk = (const float*)d_in[4];
    const float* Wv = (const float*)d_in[5];
    const float* bv = (const float*)d_in[6];
    const float* Wo = (const float*)d_in[7];
    const float* bo = (const float*)d_in[8];
    float* out = (float*)d_out;

    char* ws = (char*)d_ws;
    const size_t M = (size_t)B_ * S_;                         // 8192
    short* xb     = (short*)(ws);                             // 33,554,432 B
    short* Wqkv_t = (short*)(ws + 33554432);                  //  9,437,184
    short* Wo_t   = (short*)(ws + 42991616);                  //  8,388,608
    float* bqkv   = (float*)(ws + 51380224);                  //     16,384
    short* QKV    = (short*)(ws + 51396608);                  // 37,748,736
    short* Vtb    = (short*)(ws + 89145344);                  //  2,097,152
    short* attn   = (short*)(ws + 91242496);                  // 33,554,432
    // total: 124,796,928 B

    // casts / transposes / bias concat
    cast_f32_bf16_kernel<<<2048, 256, 0, stream>>>(x, xb, (int)(M * E_ / 4));
    transpose_cast_kernel<<<dim3(E_/32,  E_/32), 256, 0, stream>>>(Wq, Wqkv_t, E_, QKDIM_);
    transpose_cast_kernel<<<dim3(HD_/32, E_/32), 256, 0, stream>>>(Wk, Wqkv_t + (size_t)QKDIM_*E_, E_, HD_);
    transpose_cast_kernel<<<dim3(HD_/32, E_/32), 256, 0, stream>>>(Wv, Wqkv_t + (size_t)(QKDIM_+HD_)*E_, E_, HD_);
    transpose_cast_kernel<<<dim3(E_/32,  E_/32), 256, 0, stream>>>(Wo, Wo_t, QKDIM_, E_);
    concat_bias_kernel<<<9, 256, 0, stream>>>(bq, bk, bv, bqkv);

    // fused QKV projection: [8192,2048] @ [2048,2304] -> [8192,2304]
    gemm_lds_kernel<true><<<dim3(QKVLD/128, M/128), 256, 0, stream>>>(
        xb, Wqkv_t, bqkv, QKV, (int)M, QKVLD, E_);

    // V^T: [B][HD][S] from QKV's V columns
    transpose_v_kernel<<<dim3(HD_/32, S_/32, B_), 256, 0, stream>>>(
        QKV + QKDIM_ + HD_, Vtb, QKVLD);

    // attention: 256 blocks x 8 waves (8 heads sharing K via LDS), uniform work
    attn_kernel<<<256, 512, 0, stream>>>(QKV, Vtb, attn);

    // output projection (f32 out)
    gemm_lds_kernel<false><<<dim3(E_/128, M/128), 256, 0, stream>>>(
        attn, Wo_t, bo, out, (int)M, E_, E_);
}

// Round 7
// 580.064 us; speedup vs baseline: 3.8594x; 1.3874x over previous
//
#include <hip/hip_runtime.h>
#include <hip/hip_bf16.h>

#define B_  2
#define S_  4096
#define E_  2048
#define H_  16
#define HD_ 128
#define QKDIM_ (H_*HD_)   // 2048
#define QKVLD  2304       // fused QKV row stride (2048 Q + 128 K + 128 V)

typedef __attribute__((ext_vector_type(8))) short bf16x8;
typedef __attribute__((ext_vector_type(4))) float f32x4;

static __device__ __forceinline__ short f2bf(float f) {
    unsigned int u = __builtin_bit_cast(unsigned int, f);
    unsigned int r = 0x7FFFu + ((u >> 16) & 1u);
    u += r;
    return (short)(u >> 16);
}

static __device__ __forceinline__ unsigned cvt_pk_bf16(float lo, float hi) {
    unsigned r;
    asm volatile("v_cvt_pk_bf16_f32 %0, %1, %2" : "=v"(r) : "v"(lo), "v"(hi));
    return r;
}

static __device__ __forceinline__ void gload_lds16(const short* g, short* l) {
    __builtin_amdgcn_global_load_lds(
        (const __attribute__((address_space(1))) void*)g,
        (__attribute__((address_space(3))) void*)l, 16, 0, 0);
}

// ---------------- cast f32 -> bf16 (vectorized, grid-stride) ----------------
__global__ void cast_f32_bf16_kernel(const float* __restrict__ in,
                                     short* __restrict__ out, int n4) {
    int stride = gridDim.x * blockDim.x;
    for (int i = blockIdx.x * blockDim.x + threadIdx.x; i < n4; i += stride) {
        float4 v = ((const float4*)in)[i];
        short4 o;
        o.x = f2bf(v.x); o.y = f2bf(v.y); o.z = f2bf(v.z); o.w = f2bf(v.w);
        ((short4*)out)[i] = o;
    }
}

// ------------- transpose + cast: W[K,N] f32  ->  Wt[N,K] bf16 ---------------
__global__ void transpose_cast_kernel(const float* __restrict__ in,
                                      short* __restrict__ out, int K, int N) {
    __shared__ float tile[32][33];
    int nb = blockIdx.x * 32, kb = blockIdx.y * 32;
    int tx = threadIdx.x & 31, ty = threadIdx.x >> 5;   // 256 thr: 8 rows/pass
    for (int r = ty; r < 32; r += 8)
        tile[r][tx] = in[(size_t)(kb + r) * N + nb + tx];
    __syncthreads();
    for (int r = ty; r < 32; r += 8)
        out[(size_t)(nb + r) * K + kb + tx] = f2bf(tile[tx][r]);
}

// ---------------------- concat bias [bq|bk|bv] -> f32[2304] -----------------
__global__ void concat_bias_kernel(const float* __restrict__ bq,
                                   const float* __restrict__ bk,
                                   const float* __restrict__ bv,
                                   float* __restrict__ out) {
    int i = blockIdx.x * 256 + threadIdx.x;
    if (i >= QKVLD) return;
    if (i < QKDIM_)            out[i] = bq[i];
    else if (i < QKDIM_ + HD_) out[i] = bk[i - QKDIM_];
    else                       out[i] = bv[i - QKDIM_ - HD_];
}

// --------- transpose V: QKV[B*S, ld] (V cols) bf16 -> [B][HD][S] bf16 -------
__global__ void transpose_v_kernel(const short* __restrict__ in,
                                   short* __restrict__ out, int ld) {
    __shared__ short tile[32][33];
    int b = blockIdx.z;
    int db = blockIdx.x * 32, sb = blockIdx.y * 32;
    int tx = threadIdx.x & 31, ty = threadIdx.x >> 5;
    for (int r = ty; r < 32; r += 8)
        tile[r][tx] = in[(size_t)(b * S_ + sb + r) * ld + db + tx];
    __syncthreads();
    for (int r = ty; r < 32; r += 8)
        out[((size_t)b * HD_ + db + r) * S_ + sb + tx] = tile[tx][r];
}

// ------------- GEMM m97-structure: C = A @ Bt^T + bias, 128x128 tile --------
template <bool BF16OUT>
__global__ __launch_bounds__(256)
void gemm_lds_kernel(const short* __restrict__ A, const short* __restrict__ Bt,
                     const float* __restrict__ bias, void* __restrict__ Cout,
                     int M, int N, int Kd) {
    __shared__ short smA[128 * 32];
    __shared__ short smB[128 * 32];
    int wave = threadIdx.x >> 6;
    int lane = threadIdx.x & 63;
    int wr = wave >> 1, wc = wave & 1;
    int row_blk = blockIdx.y * 128, col_blk = blockIdx.x * 128;
    int lr = lane & 15;
    int lk = (lane >> 4) * 8;

    int srow = lane >> 2;              // 0..15
    int scol = (lane & 3) * 8;         // 0,8,16,24
    const short* gA = A  + (size_t)(row_blk + wave*32 + srow) * Kd + scol;
    const short* gB = Bt + (size_t)(col_blk + wave*32 + srow) * Kd + scol;
    short* lA = smA + wave * 32 * 32;
    short* lB = smB + wave * 32 * 32;

    f32x4 acc[4][4] = {};
    for (int k0 = 0; k0 < Kd; k0 += 32) {
        __syncthreads();
        gload_lds16(gA + k0,                 lA);
        gload_lds16(gA + k0 + (size_t)16*Kd, lA + 16*32);
        gload_lds16(gB + k0,                 lB);
        gload_lds16(gB + k0 + (size_t)16*Kd, lB + 16*32);
        __syncthreads();

        bf16x8 af[4], bfr[4];
#pragma unroll
        for (int i = 0; i < 4; i++) {
            af[i]  = *(const bf16x8*)&smA[(wr*64 + i*16 + lr) * 32 + lk];
            bfr[i] = *(const bf16x8*)&smB[(wc*64 + i*16 + lr) * 32 + lk];
        }
#pragma unroll
        for (int i = 0; i < 4; i++)
#pragma unroll
            for (int j = 0; j < 4; j++)
                acc[i][j] = __builtin_amdgcn_mfma_f32_16x16x32_bf16(
                    af[i], bfr[j], acc[i][j], 0, 0, 0);
    }
    int crow = (lane >> 4) * 4;
    int ccol = lane & 15;
#pragma unroll
    for (int i = 0; i < 4; i++)
#pragma unroll
        for (int j = 0; j < 4; j++)
#pragma unroll
            for (int r = 0; r < 4; r++) {
                int row = row_blk + wr*64 + i*16 + crow + r;
                int col = col_blk + wc*64 + j*16 + ccol;
                float v = acc[i][j][r] + bias[col];
                if (BF16OUT)
                    ((short*)Cout)[(size_t)row * N + col] = f2bf(v);
                else
                    ((float*)Cout)[(size_t)row * N + col] = v;
            }
}

// --------------------------- flash MQA attention v7 -------------------------
// Block = 8 waves = 8 heads share K AND V tiles via double-buffered swizzled
// LDS (MQA: identical K/V across heads). V read from LDS at PV time -> no
// 64-VGPR V prefetch -> no spill. waves_per_eu(2,2) pins the 256-VGPR budget.
static __device__ __forceinline__ f32x4 mfma16(bf16x8 a, bf16x8 b, f32x4 c) {
    return __builtin_amdgcn_mfma_f32_16x16x32_bf16(a, b, c, 0, 0, 0);
}

template <bool MASK>
static __device__ __forceinline__ void attn_step(
    const short* __restrict__ ks,      // LDS K tile [64 keys][128 d] swizzled
    const short* __restrict__ vs,      // LDS V tile [128 d][64 keys] swizzled
    short (*pw)[72],                   // per-wave P [32 q][64 keys](+pad)
    const bf16x8 (&qf)[2][4],
    f32x4 (&o)[2][8], float (&m)[2], float (&l)[2],
    int q0, int key0, int lane)
{
    const int g = lane >> 4, c = lane & 15;
    const int crow = g * 4;
    const float scale = 0.08838834764831845f;  // 1/sqrt(128)

    // ---- QK^T swapped, K from swizzled LDS
    f32x4 s[2][4] = {};
    __builtin_amdgcn_s_setprio(1);
#pragma unroll
    for (int kk = 0; kk < 4; kk++) {
        bf16x8 kfk[4];
#pragma unroll
        for (int kt = 0; kt < 4; kt++)
            kfk[kt] = *(const bf16x8*)&ks[(kt*16 + c)*128 + (((kk*4 + g) ^ (c & 7))*8)];
#pragma unroll
        for (int i = 0; i < 2; i++)
#pragma unroll
            for (int kt = 0; kt < 4; kt++)
                s[i][kt] = mfma16(kfk[kt], qf[i][kk], s[i][kt]);
    }
    __builtin_amdgcn_s_setprio(0);

    // ---- softmax per i-tile (in-register along keys), P -> LDS [32][72]
#pragma unroll
    for (int i = 0; i < 2; i++) {
        float v[16];
#pragma unroll
        for (int kt = 0; kt < 4; kt++)
#pragma unroll
            for (int r = 0; r < 4; r++) {
                float val = s[i][kt][r] * scale;
                if (MASK && key0 + kt*16 + crow + r > q0 + i*16 + c) val = -1e30f;
                v[kt*4 + r] = val;
            }
        float t8[8];
#pragma unroll
        for (int k = 0; k < 8; k++) t8[k] = fmaxf(v[k], v[k+8]);
        float t4a = fmaxf(t8[0], t8[4]), t4b = fmaxf(t8[1], t8[5]);
        float t4c = fmaxf(t8[2], t8[6]), t4d = fmaxf(t8[3], t8[7]);
        float mx = fmaxf(fmaxf(t4a, t4b), fmaxf(t4c, t4d));
        mx = fmaxf(mx, __shfl_xor(mx, 16));
        mx = fmaxf(mx, __shfl_xor(mx, 32));
        float mn = fmaxf(m[i], mx);
        float corr = __expf(m[i] - mn);
        m[i] = mn;
        float e[16];
#pragma unroll
        for (int k = 0; k < 16; k++) e[k] = __expf(v[k] - mn);
#pragma unroll
        for (int kt = 0; kt < 4; kt++) {
            uint2 w;
            w.x = cvt_pk_bf16(e[kt*4+0], e[kt*4+1]);
            w.y = cvt_pk_bf16(e[kt*4+2], e[kt*4+3]);
            *(uint2*)&pw[i*16 + c][kt*16 + crow] = w;
        }
        float s8[8];
#pragma unroll
        for (int k = 0; k < 8; k++) s8[k] = e[k] + e[k+8];
        float rs = ((s8[0]+s8[4]) + (s8[1]+s8[5])) + ((s8[2]+s8[6]) + (s8[3]+s8[7]));
        rs += __shfl_xor(rs, 16);
        rs += __shfl_xor(rs, 32);
        l[i] = l[i] * corr + rs;
        float corrR[4];
#pragma unroll
        for (int r = 0; r < 4; r++) corrR[r] = __shfl(corr, crow + r);
#pragma unroll
        for (int j = 0; j < 8; j++)
#pragma unroll
            for (int r = 0; r < 4; r++)
                o[i][j][r] *= corrR[r];
    }

    // ---- PV: P from LDS (A-layout), V fragments from shared LDS tile
    __builtin_amdgcn_s_setprio(1);
#pragma unroll
    for (int ks2 = 0; ks2 < 2; ks2++) {
        bf16x8 pf0 = *(const bf16x8*)&pw[c]     [ks2*32 + g*8];
        bf16x8 pf1 = *(const bf16x8*)&pw[16 + c][ks2*32 + g*8];
#pragma unroll
        for (int j = 0; j < 8; j++) {
            bf16x8 vf = *(const bf16x8*)&vs[(j*16 + c)*64 + (((ks2*4 + g) ^ (c & 7))*8)];
            o[0][j] = mfma16(pf0, vf, o[0][j]);
            o[1][j] = mfma16(pf1, vf, o[1][j]);
        }
    }
    __builtin_amdgcn_s_setprio(0);
}

__global__ __launch_bounds__(512) __attribute__((amdgpu_waves_per_eu(2, 2)))
void attn_kernel(const short* __restrict__ QKV, const short* __restrict__ Vt,
                 short* __restrict__ Out) {
    __shared__ __align__(16) short ksm[2][64 * 128];     // 2 x 16 KB
    __shared__ __align__(16) short vsm[2][128 * 64];     // 2 x 16 KB
    __shared__ __align__(16) short plds_all[8][32][72];  // 36.9 KB
    int wave = threadIdx.x >> 6;
    int lane = threadIdx.x & 63;
    int bb = blockIdx.x;                 // 0..255
    int tt = bb & 63;
    int hg = (bb >> 6) & 1;
    int b  = bb >> 7;
    int h  = hg * 8 + wave;
    short (*pw)[72] = plds_all[wave];
    int g = lane >> 4, c = lane & 15;
    int crow = g * 4;

    const short* qkv_b = QKV + (size_t)b * S_ * QKVLD;
    const short* vtb_b = Vt + (size_t)b * HD_ * S_;
    const short* kb0   = qkv_b + QKDIM_;

    auto stage = [&](int buf, int key0) {
        // K tile: [64 keys][16 chunks], chunk swizzled by (row&7)
#pragma unroll
        for (int q = 0; q < 2; q++) {
            int ci  = wave*128 + q*64 + lane;
            int row = ci >> 4;                  // key row 0..63
            int cc  = (ci & 15) ^ (row & 7);    // inverse-swizzled source chunk
            gload_lds16(kb0 + (size_t)(key0 + row) * QKVLD + cc*8,
                        &ksm[buf][(wave*128 + q*64) * 8]);
        }
        // V tile: [128 d][8 chunks], chunk swizzled by (row&7)
#pragma unroll
        for (int q = 0; q < 2; q++) {
            int ci  = wave*128 + q*64 + lane;
            int row = ci >> 3;                  // d row 0..127
            int cc  = (ci & 7) ^ (row & 7);     // inverse-swizzled source chunk
            gload_lds16(vtb_b + (size_t)row * S_ + key0 + cc*8,
                        &vsm[buf][(wave*128 + q*64) * 8]);
        }
    };

#pragma unroll 1
    for (int phase = 0; phase < 2; phase++) {
        int t  = phase ? tt : (127 - tt);       // within-wave pairing: uniform
        int q0 = t * 32;
        bf16x8 qf[2][4];
#pragma unroll
        for (int i = 0; i < 2; i++)
#pragma unroll
            for (int kk = 0; kk < 4; kk++)
                qf[i][kk] = *(const bf16x8*)&qkv_b[(size_t)(q0 + i*16 + c) * QKVLD
                                                   + h*HD_ + kk*32 + g*8];
        f32x4 o[2][8] = {};
        float m[2] = {-1e30f, -1e30f}, l[2] = {0.f, 0.f};

        int nb = q0 / 64 + 1;
        int cur = 0;
        __syncthreads();                        // WAR guard across phases
        stage(0, 0);
#pragma unroll 1
        for (int kb = 0; kb < nb; kb++) {
            __syncthreads();                    // drains vmcnt: buffers ready
            if (kb + 1 < nb) stage(cur ^ 1, (kb + 1) * 64);
            if (kb == nb - 1)
                attn_step<true >(ksm[cur], vsm[cur], pw, qf, o, m, l, q0, kb*64, lane);
            else
                attn_step<false>(ksm[cur], vsm[cur], pw, qf, o, m, l, q0, kb*64, lane);
            cur ^= 1;
        }

        // epilogue: transpose l to row form, normalize, store
#pragma unroll
        for (int i = 0; i < 2; i++) {
            float linv[4];
#pragma unroll
            for (int r = 0; r < 4; r++) linv[r] = 1.0f / __shfl(l[i], crow + r);
#pragma unroll
            for (int j = 0; j < 8; j++)
#pragma unroll
                for (int r = 0; r < 4; r++) {
                    int row = q0 + i*16 + crow + r;
                    Out[(size_t)(b*S_ + row) * QKDIM_ + h*HD_ + j*16 + c] =
                        f2bf(o[i][j][r] * linv[r]);
                }
        }
    }
}

// ------------------------------- launcher -----------------------------------
extern "C" void kernel_launch(void* const* d_in, const int* in_sizes, int n_in,
                              void* d_out, int out_size, void* d_ws, size_t ws_size,
                              hipStream_t stream) {
    (void)in_sizes; (void)n_in; (void)out_size; (void)ws_size;
    const float* x  = (const float*)d_in[0];
    const float* Wq = (const float*)d_in[1];
    const float* bq = (const float*)d_in[2];
    const float* Wk = (const float*)d_in[3];
    const float* bk = (const float*)d_in[4];
    const float* Wv = (const float*)d_in[5];
    const float* bv = (const float*)d_in[6];
    const float* Wo = (const float*)d_in[7];
    const float* bo = (const float*)d_in[8];
    float* out = (float*)d_out;

    char* ws = (char*)d_ws;
    const size_t M = (size_t)B_ * S_;                         // 8192
    short* xb     = (short*)(ws);                             // 33,554,432 B
    short* Wqkv_t = (short*)(ws + 33554432);                  //  9,437,184
    short* Wo_t   = (short*)(ws + 42991616);                  //  8,388,608
    float* bqkv   = (float*)(ws + 51380224);                  //     16,384
    short* QKV    = (short*)(ws + 51396608);                  // 37,748,736
    short* Vtb    = (short*)(ws + 89145344);                  //  2,097,152
    short* attn   = (short*)(ws + 91242496);                  // 33,554,432
    // total: 124,796,928 B

    // casts / transposes / bias concat
    cast_f32_bf16_kernel<<<2048, 256, 0, stream>>>(x, xb, (int)(M * E_ / 4));
    transpose_cast_kernel<<<dim3(E_/32,  E_/32), 256, 0, stream>>>(Wq, Wqkv_t, E_, QKDIM_);
    transpose_cast_kernel<<<dim3(HD_/32, E_/32), 256, 0, stream>>>(Wk, Wqkv_t + (size_t)QKDIM_*E_, E_, HD_);
    transpose_cast_kernel<<<dim3(HD_/32, E_/32), 256, 0, stream>>>(Wv, Wqkv_t + (size_t)(QKDIM_+HD_)*E_, E_, HD_);
    transpose_cast_kernel<<<dim3(E_/32,  E_/32), 256, 0, stream>>>(Wo, Wo_t, QKDIM_, E_);
    concat_bias_kernel<<<9, 256, 0, stream>>>(bq, bk, bv, bqkv);

    // fused QKV projection: [8192,2048] @ [2048,2304] -> [8192,2304]
    gemm_lds_kernel<true><<<dim3(QKVLD/128, M/128), 256, 0, stream>>>(
        xb, Wqkv_t, bqkv, QKV, (int)M, QKVLD, E_);

    // V^T: [B][HD][S] from QKV's V columns
    transpose_v_kernel<<<dim3(HD_/32, S_/32, B_), 256, 0, stream>>>(
        QKV + QKDIM_ + HD_, Vtb, QKVLD);

    // attention: 256 blocks x 8 waves (8 heads sharing K+V via LDS), uniform
    attn_kernel<<<256, 512, 0, stream>>>(QKV, Vtb, attn);

    // output projection (f32 out)
    gemm_lds_kernel<false><<<dim3(E_/128, M/128), 256, 0, stream>>>(
        attn, Wo_t, bo, out, (int)M, E_, E_);
}